// Round 3
// baseline (248.425 us; speedup 1.0000x reference)
//
#include <hip/hip_runtime.h>
#include <hip/hip_fp16.h>

#define HID 64
#define NGRAPHS 256
#define CHUNK 4096        // edges per pass-1 chunk (306 blocks > 256 CUs)
#define BKTSZ 512         // nodes per coarse bucket
#define BKTSH 9
#define PSH 17            // src fits in 17 bits (N <= 131072)
#define PMASK 0x1FFFF

typedef _Float16 half8 __attribute__((ext_vector_type(8)));
typedef float f32x4 __attribute__((ext_vector_type(4)));

// MEASURED LAWS (R1-R20):
//  - scattered device-scope atomics/stores write through ~64B lines at
//    ~0.9 TB/s; same-line fp32 atomics ~15 G/s -> LDS counting-sort CSR.
//  - grid.sync() coop barrier ~100us at full grid (R13) -> discrete
//    launches (~6-7us/boundary) are strictly cheaper here.
//  - R14: narrow-grid fusion serializes wide phases; R17: same-grid
//    fusion (agg+gemm) wins. R15: >8-wide gather unroll regresses.
//  - R18: slot-packed scatter + per-edge binary-search rebuild (60us)
//    loses to the 3-pass scan pipeline (25+5+7us). Keep the scan.
//  - R19 DISASTER: per-graph global fp32 atomics + __threadfence per
//    block inside the layer-3 aggregate made the GATHER phase 4x slower.
//    Device-scope fences/atomics poison L2-resident gather throughput.
//  - R20: per-block partial-sum stores + tiny pool launch -> 236us.
// R21 (this round): (1) cooperative csr loads (1 coalesced load + shfl
//    broadcast per 8/4-batch instead of 8 serialized uniform loads) --
//    attacks the csr-load->gather dependency chain; (2) gemm7 fused as a
//    tail phase of csr_build (dinv for the bucket's own 512 nodes is in
//    LDS cnt[]) -- removes one launch+boundary.

// ---- P0: prepW (blocks 0-1) + per-chunk coarse histogram ----------------

__global__ __launch_bounds__(256) void k_hist(
        const int* __restrict__ dst, const float* __restrict__ W2,
        const float* __restrict__ W3, __half* __restrict__ Wf2,
        __half* __restrict__ Wf3, int* __restrict__ H,
        float* __restrict__ gsum, int e, int nbkt, int nchunk) {
    __shared__ int cnt4[4][256];    // per-wave split: 4x less contention
    const int t = threadIdx.x, b = blockIdx.x;
    const int gtid = b * 256 + t;
    if (gtid < 512) {       // W fragment repack: 16x16x32-f16 B layout
        int p = gtid;
        int kt = p >> 8, c = (p >> 6) & 3, lane = p & 63;
        int quad = lane >> 4, m = lane & 15;
#pragma unroll
        for (int j = 0; j < 8; ++j) {
            int k = kt * 32 + quad * 8 + j;
            int ch = c * 16 + m;
            Wf2[(size_t)p * 8 + j] = __float2half(W2[k * HID + ch]);
            Wf3[(size_t)p * 8 + j] = __float2half(W3[k * HID + ch]);
        }
    }
    if (b == 0) {           // zero the (rare-case) pool spill accumulator
        for (int i = t; i < NGRAPHS * HID; i += 256) gsum[i] = 0.0f;
    }
    for (int i = t; i < 1024; i += 256) ((int*)cnt4)[i] = 0;
    __syncthreads();
    const int w = t >> 6;
#pragma unroll
    for (int it = 0; it < CHUNK / 1024; ++it) {
        int idx = b * CHUNK + it * 1024 + t * 4;
        if (idx + 3 < e) {
            int4 d = *(const int4*)(dst + idx);
            atomicAdd(&cnt4[w][d.x >> BKTSH], 1);
            atomicAdd(&cnt4[w][d.y >> BKTSH], 1);
            atomicAdd(&cnt4[w][d.z >> BKTSH], 1);
            atomicAdd(&cnt4[w][d.w >> BKTSH], 1);
        } else {
            for (int i = idx; i < e && i < idx + 4; ++i)
                atomicAdd(&cnt4[w][dst[i] >> BKTSH], 1);
        }
    }
    __syncthreads();
    for (int i = t; i < nbkt; i += 256)
        H[i * nchunk + b] = cnt4[0][i] + cnt4[1][i] + cnt4[2][i] + cnt4[3][i];
}

// ---- P1: per-1024 partial exclusive scans + block sums ------------------

__global__ __launch_bounds__(256) void k_scan(const int* __restrict__ in,
                                              int* __restrict__ outp,
                                              int* __restrict__ bsum, int n) {
    __shared__ int sh[256];
    const int t = threadIdx.x;
    const int base = blockIdx.x * 1024 + t * 4;
    int v[4];
    int s = 0;
#pragma unroll
    for (int k = 0; k < 4; k++) {
        int i = base + k;
        v[k] = (i < n) ? in[i] : 0;
        s += v[k];
    }
    sh[t] = s;
    __syncthreads();
#pragma unroll
    for (int off = 1; off < 256; off <<= 1) {
        int add = (t >= off) ? sh[t - off] : 0;
        __syncthreads();
        sh[t] += add;
        __syncthreads();
    }
    int run = sh[t] - s;
#pragma unroll
    for (int k = 0; k < 4; k++) {
        int i = base + k;
        if (i < n) outp[i] = run;
        run += v[k];
    }
    if (t == 255) bsum[blockIdx.x] = sh[255];
}

// ---- P2: bucket scatter (packed 4B, coalesced runs) ---------------------

__global__ __launch_bounds__(256) void k_scatter(
        const int* __restrict__ src, const int* __restrict__ dst,
        const int* __restrict__ Hs, const int* __restrict__ bsum,
        int* __restrict__ packed, int e, int nbkt, int nchunk, int nscan) {
    __shared__ int off[256];
    __shared__ int lc[256];
    __shared__ int bscan[64];
    const int t = threadIdx.x, b = blockIdx.x;
    if (t < 64) bscan[t] = (t < nscan) ? bsum[t] : 0;
    __syncthreads();
#pragma unroll
    for (int o = 1; o < 64; o <<= 1) {
        int add = (t < 64 && t >= o) ? bscan[t - o] : 0;
        __syncthreads();
        if (t < 64) bscan[t] += add;
        __syncthreads();
    }
    for (int i = t; i < nbkt; i += 256) {
        int idx = i * nchunk + b;
        int q = idx >> 10;
        off[i] = Hs[idx] + (q ? bscan[q - 1] : 0);
        lc[i] = 0;
    }
    __syncthreads();
#pragma unroll
    for (int it = 0; it < CHUNK / 1024; ++it) {
        int idx = b * CHUNK + it * 1024 + t * 4;
        if (idx + 3 < e) {
            int4 d = *(const int4*)(dst + idx);
            int4 s = *(const int4*)(src + idx);
            int b0 = d.x >> BKTSH, b1 = d.y >> BKTSH;
            int b2 = d.z >> BKTSH, b3 = d.w >> BKTSH;
            int r0 = atomicAdd(&lc[b0], 1);
            int r1 = atomicAdd(&lc[b1], 1);
            int r2 = atomicAdd(&lc[b2], 1);
            int r3 = atomicAdd(&lc[b3], 1);
            packed[off[b0] + r0] = s.x | ((d.x & (BKTSZ - 1)) << PSH);
            packed[off[b1] + r1] = s.y | ((d.y & (BKTSZ - 1)) << PSH);
            packed[off[b2] + r2] = s.z | ((d.z & (BKTSZ - 1)) << PSH);
            packed[off[b3] + r3] = s.w | ((d.w & (BKTSZ - 1)) << PSH);
        } else {
            for (int i = idx; i < e && i < idx + 4; ++i) {
                int dd = dst[i];
                int bk = dd >> BKTSH;
                int r = atomicAdd(&lc[bk], 1);
                packed[off[bk] + r] = src[i] | ((dd & (BKTSZ - 1)) << PSH);
            }
        }
    }
}

// ---- P3: per-bucket local CSR build + FUSED layer-1 gemm (R21) ----------
// After CSR work, this block's 512 nodes' dinv is sitting in LDS cnt[],
// so the K=7 layer-1 gemm for exactly those nodes runs as a tail phase:
// h1[n] = (x[n] @ W1) * dinv[n], written fp16. No cross-block dependency.

__global__ __launch_bounds__(256) void k_csr_build(
        const int* __restrict__ packed, const int* __restrict__ Hs,
        const int* __restrict__ bsum, int* __restrict__ rowptr,
        float* __restrict__ dinv, int* __restrict__ csr,
        const float* __restrict__ x, const float* __restrict__ W1,
        __half* __restrict__ h1,
        int e, int n, int nbkt, int nchunk, int nscan) {
    __shared__ int cnt[BKTSZ];
    __shared__ int pref[BKTSZ];
    __shared__ int ssum[256];
    __shared__ int cnt2[BKTSZ];
    __shared__ int bscan[64];
    __shared__ float Wsh[7 * HID];
    __shared__ float Xsh[BKTSZ * 7];
    const int t = threadIdx.x, bkt = blockIdx.x;
    if (t < 64) bscan[t] = (t < nscan) ? bsum[t] : 0;
    if (bkt == 0 && t == 0) rowptr[n] = e;
    // stage W1 + this bucket's x rows early (consumed at the tail)
    for (int i = t; i < 7 * HID; i += 256) Wsh[i] = W1[i];
    {
        const int xbase = bkt * BKTSZ * 7;
        const int xlim = n * 7 - xbase;
        for (int i = t; i < BKTSZ * 7; i += 256)
            Xsh[i] = (i < xlim) ? x[xbase + i] : 0.0f;
    }
    cnt[t] = 0; cnt[t + 256] = 0;
    cnt2[t] = 0; cnt2[t + 256] = 0;
    __syncthreads();
#pragma unroll
    for (int o = 1; o < 64; o <<= 1) {
        int add = (t < 64 && t >= o) ? bscan[t - o] : 0;
        __syncthreads();
        if (t < 64) bscan[t] += add;
        __syncthreads();
    }
    int i0 = bkt * nchunk;
    int q0 = i0 >> 10;
    int segStart = Hs[i0] + (q0 ? bscan[q0 - 1] : 0);
    int segEnd = e;
    if (bkt + 1 < nbkt) {
        int i1 = (bkt + 1) * nchunk;
        int q1 = i1 >> 10;
        segEnd = Hs[i1] + (q1 ? bscan[q1 - 1] : 0);
    }
    for (int j = segStart + t; j < segEnd; j += 256)
        atomicAdd(&cnt[(packed[j] >> PSH) & (BKTSZ - 1)], 1);
    __syncthreads();
    int a0 = cnt[2 * t], a1 = cnt[2 * t + 1];
    int s = a0 + a1;
    ssum[t] = s;
    __syncthreads();
#pragma unroll
    for (int off = 1; off < 256; off <<= 1) {
        int add = (t >= off) ? ssum[t - off] : 0;
        __syncthreads();
        ssum[t] += add;
        __syncthreads();
    }
    int p = ssum[t] - s;
    pref[2 * t] = p;
    pref[2 * t + 1] = p + a0;
    __syncthreads();
    for (int i = t; i < BKTSZ; i += 256) {
        int node = bkt * BKTSZ + i;
        if (node < n) {
            rowptr[node] = segStart + pref[i];
            dinv[node] = rsqrtf((float)(cnt[i] + 1));   // +1 self-loop
        }
    }
    for (int j = segStart + t; j < segEnd; j += 256) {
        int pk = packed[j];
        int ld = (pk >> PSH) & (BKTSZ - 1);
        int r = atomicAdd(&cnt2[ld], 1);
        csr[segStart + pref[ld] + r] = pk & PMASK;
    }
    // ---- tail: layer-1 gemm for this bucket's nodes (cnt[] still valid)
    const int c = t & 63;
    const int g = t >> 6;
    for (int it2 = 0; it2 < BKTSZ / 4; ++it2) {
        int nl = it2 * 4 + g;
        int node = bkt * BKTSZ + nl;
        if (node >= n) break;          // uniform within each wave
        float acc = 0.0f;
#pragma unroll
        for (int k = 0; k < 7; ++k)
            acc += Xsh[nl * 7 + k] * Wsh[k * HID + c];
        float dv = rsqrtf((float)(cnt[nl] + 1));
        h1[(size_t)node * HID + c] = __float2half(acc * dv);
    }
}

__device__ __forceinline__ float4 h4_to_f4(int2 raw) {
    __half2 p0 = *(__half2*)&raw.x;
    __half2 p1 = *(__half2*)&raw.y;
    float2 f0 = __half22float2(p0);
    float2 f1 = __half22float2(p1);
    return make_float4(f0.x, f0.y, f1.x, f1.y);
}

// ---- FUSED aggregate + MFMA gemm (layers 1->2, 2->3) --------------------
// R21 gather: one coalesced 16-lane csr load feeds 8 (or 4) gathers via
// __shfl broadcast -- removes the 8 serialized uniform csr loads per batch.

__global__ __launch_bounds__(256) void k_agg_gemm(
        const int* __restrict__ rowptr, const int* __restrict__ csr,
        const __half* __restrict__ h, const float* __restrict__ b,
        const float* __restrict__ dinv, const __half* __restrict__ Wf,
        __half* __restrict__ hout, int n_nodes) {
    __shared__ __half act[16 * 72];
    const int t = threadIdx.x;
    const int n0 = blockIdx.x * 16;
    const int nl = t >> 4;          // local node 0..15
    const int node = n0 + nl;
    const int l16 = t & 15;
    const int2* h8 = (const int2*)h;
    const float4* b4 = (const float4*)b;

    float4 av = make_float4(0.0f, 0.0f, 0.0f, 0.0f);
    if (node < n_nodes) {
        int beg = rowptr[node], end = rowptr[node + 1];
        float dv = dinv[node];
        float4 inner = h4_to_f4(h8[(size_t)node * 16 + l16]);   // self h'
        int j = beg;
        for (; j + 7 < end; j += 8) {       // 1 coalesced csr load / 8 edges
            int e8 = csr[j + (l16 & 7)];
            int2 r[8];
#pragma unroll
            for (int q = 0; q < 8; ++q)
                r[q] = h8[(size_t)__shfl(e8, q, 8) * 16 + l16];
#pragma unroll
            for (int q = 0; q < 8; ++q) {
                float4 v = h4_to_f4(r[q]);
                inner.x += v.x; inner.y += v.y; inner.z += v.z; inner.w += v.w;
            }
        }
        if (j + 3 < end) {
            int e4 = csr[j + (l16 & 3)];
            int2 r[4];
#pragma unroll
            for (int q = 0; q < 4; ++q)
                r[q] = h8[(size_t)__shfl(e4, q, 4) * 16 + l16];
#pragma unroll
            for (int q = 0; q < 4; ++q) {
                float4 v = h4_to_f4(r[q]);
                inner.x += v.x; inner.y += v.y; inner.z += v.z; inner.w += v.w;
            }
            j += 4;
        }
        for (; j < end; j++) {
            float4 v = h4_to_f4(h8[(size_t)csr[j] * 16 + l16]);
            inner.x += v.x; inner.y += v.y; inner.z += v.z; inner.w += v.w;
        }
        float4 bb = b4[l16];
        av.x = fmaxf(bb.x + dv * inner.x, 0.0f);   // relu(agg) = gemm input
        av.y = fmaxf(bb.y + dv * inner.y, 0.0f);
        av.z = fmaxf(bb.z + dv * inner.z, 0.0f);
        av.w = fmaxf(bb.w + dv * inner.w, 0.0f);
    }
    {   // stage act tile: row nl, cols l16*4..+3 (8B store)
        __half2 p0 = __floats2half2_rn(av.x, av.y);
        __half2 p1 = __floats2half2_rn(av.z, av.w);
        int2 pk;
        pk.x = *(int*)&p0;
        pk.y = *(int*)&p1;
        *(int2*)&act[nl * 72 + l16 * 4] = pk;
    }
    __syncthreads();

    const int wave = t >> 6, lane = t & 63;
    const int quad = lane >> 4, m = lane & 15;
    const half8* Wf8 = (const half8*)Wf;
    f32x4 acc = {0.0f, 0.0f, 0.0f, 0.0f};
#pragma unroll
    for (int kt = 0; kt < 2; ++kt) {
        half8 a = *(const half8*)&act[m * 72 + kt * 32 + quad * 8];
        half8 bv = Wf8[(kt * 4 + wave) * 64 + lane];
        acc = __builtin_amdgcn_mfma_f32_16x16x32_f16(a, bv, acc, 0, 0, 0);
    }
#pragma unroll
    for (int r = 0; r < 4; ++r) {
        int nd = n0 + quad * 4 + r;
        if (nd < n_nodes)
            hout[(size_t)nd * HID + wave * 16 + m] =
                __float2half(acc[r] * dinv[nd]);
    }
}

// ---- layer-3 aggregate -> per-block per-graph PARTIAL sums (R20) --------

__global__ __launch_bounds__(256) void k_agg_part(
        const int* __restrict__ rowptr, const int* __restrict__ csr,
        const __half* __restrict__ h, const float* __restrict__ b,
        const float* __restrict__ dinv, const int* __restrict__ batch,
        float* __restrict__ partv, int* __restrict__ partg,
        float* __restrict__ gsum, int n_nodes) {
    __shared__ float redbuf[16][64];
    __shared__ int bg[16];
    const int t = threadIdx.x;
    const int n0 = blockIdx.x * 16;
    const int nl = t >> 4;
    const int node = n0 + nl;
    const int l16 = t & 15;
    const int2* h8 = (const int2*)h;
    const float4* b4 = (const float4*)b;

    if (t < 16) {
        int nd = n0 + t;
        bg[t] = (nd < n_nodes) ? batch[nd] : -1;
    }

    float4 res = make_float4(0.0f, 0.0f, 0.0f, 0.0f);
    if (node < n_nodes) {
        int beg = rowptr[node], end = rowptr[node + 1];
        float dv = dinv[node];
        float4 inner = h4_to_f4(h8[(size_t)node * 16 + l16]);   // self h'
        int j = beg;
        for (; j + 7 < end; j += 8) {       // 1 coalesced csr load / 8 edges
            int e8 = csr[j + (l16 & 7)];
            int2 r[8];
#pragma unroll
            for (int q = 0; q < 8; ++q)
                r[q] = h8[(size_t)__shfl(e8, q, 8) * 16 + l16];
#pragma unroll
            for (int q = 0; q < 8; ++q) {
                float4 v = h4_to_f4(r[q]);
                inner.x += v.x; inner.y += v.y; inner.z += v.z; inner.w += v.w;
            }
        }
        if (j + 3 < end) {
            int e4 = csr[j + (l16 & 3)];
            int2 r[4];
#pragma unroll
            for (int q = 0; q < 4; ++q)
                r[q] = h8[(size_t)__shfl(e4, q, 4) * 16 + l16];
#pragma unroll
            for (int q = 0; q < 4; ++q) {
                float4 v = h4_to_f4(r[q]);
                inner.x += v.x; inner.y += v.y; inner.z += v.z; inner.w += v.w;
            }
            j += 4;
        }
        for (; j < end; j++) {
            float4 v = h4_to_f4(h8[(size_t)csr[j] * 16 + l16]);
            inner.x += v.x; inner.y += v.y; inner.z += v.z; inner.w += v.w;
        }
        float4 bb = b4[l16];
        res.x = bb.x + dv * inner.x;                   // layer 3: NO relu
        res.y = bb.y + dv * inner.y;
        res.z = bb.z + dv * inner.z;
        res.w = bb.w + dv * inner.w;
    }
    *(float4*)&redbuf[nl][l16 * 4] = res;
    __syncthreads();

    if (t < 64) {           // one wave: run-length reduce 16 rows -> 2 slots
        const int c = t;
        const int g0 = bg[0];
        const int g15 = bg[15];
        float s0 = 0.0f, s1 = 0.0f;
        for (int i = 0; i < 16; ++i) {
            int g = bg[i];
            float v = redbuf[i][c];
            if (g == g0) s0 += v;
            else if (g == g15) s1 += v;
            else if (g >= 0) atomicAdd(&gsum[g * HID + c], v);  // ~never
        }
        partv[(size_t)blockIdx.x * 128 + c] = s0;
        partv[(size_t)blockIdx.x * 128 + 64 + c] = s1;
        if (c == 0) {
            partg[blockIdx.x * 2 + 0] = g0;
            partg[blockIdx.x * 2 + 1] = (g15 != g0) ? g15 : -1;
        }
    }
}

// ---- mean-pool over partials + head: one block per graph ----------------

__global__ __launch_bounds__(256) void k_pool_head(
        const float* __restrict__ partv, const int* __restrict__ partg,
        const float* __restrict__ gsum, const int* __restrict__ batch,
        const float* __restrict__ Wl, const float* __restrict__ bl,
        float* __restrict__ out, int n_nodes) {
    int g = blockIdx.x;
    int lo = 0, hi = n_nodes;
    while (lo < hi) { int m = (lo + hi) >> 1; if (batch[m] < g) lo = m + 1; else hi = m; }
    int nstart = lo;
    hi = n_nodes;
    while (lo < hi) { int m = (lo + hi) >> 1; if (batch[m] < g + 1) lo = m + 1; else hi = m; }
    int nend = lo;

    int c = threadIdx.x & 63, part = threadIdx.x >> 6;
    float acc = 0.0f;
    if (nend > nstart) {
        int b0 = nstart >> 4, b1 = (nend - 1) >> 4;
        for (int b = b0 + part; b <= b1; b += 4) {
            if (partg[b * 2 + 0] == g) acc += partv[(size_t)b * 128 + c];
            if (partg[b * 2 + 1] == g) acc += partv[(size_t)b * 128 + 64 + c];
        }
    }

    __shared__ float red[4][64];
    __shared__ float hd[128];
    red[part][c] = acc;
    __syncthreads();
    if (threadIdx.x < 64) {
        float cntf = (float)(nend - nstart);
        float pooled = (red[0][c] + red[1][c] + red[2][c] + red[3][c]
                        + gsum[g * HID + c]) / fmaxf(cntf, 1.0f);
        hd[c] = pooled * Wl[c * 2 + 0];
        hd[64 + c] = pooled * Wl[c * 2 + 1];
    }
    __syncthreads();
    if (threadIdx.x < 2) {
        float s = 0.0f;
        for (int k = 0; k < 64; k++) s += hd[threadIdx.x * 64 + k];
        out[g * 2 + threadIdx.x] = s + bl[threadIdx.x];
    }
}

// -------------------------------------------------------------------------

extern "C" void kernel_launch(void* const* d_in, const int* in_sizes, int n_in,
                              void* d_out, int out_size, void* d_ws, size_t ws_size,
                              hipStream_t stream) {
    const float* x     = (const float*)d_in[0];
    const int*   ei    = (const int*)d_in[1];
    const int*   batch = (const int*)d_in[2];
    const float* W1    = (const float*)d_in[3];
    const float* b1    = (const float*)d_in[4];
    const float* W2    = (const float*)d_in[5];
    const float* b2    = (const float*)d_in[6];
    const float* W3    = (const float*)d_in[7];
    const float* b3    = (const float*)d_in[8];
    const float* Wl    = (const float*)d_in[9];
    const float* bl    = (const float*)d_in[10];
    float* out = (float*)d_out;

    const int N = in_sizes[0] / 7;     // 100000
    const int E = in_sizes[1] / 2;     // 1250000
    const int* src = ei;
    const int* dst = ei + E;

    const int nbkt   = (N + BKTSZ - 1) >> BKTSH;          // 196
    const int nchunk = (E + CHUNK - 1) / CHUNK;           // 306
    const int lenH   = nbkt * nchunk;
    const int nscan  = (lenH + 1023) / 1024;              // 59 (<=64)

    char* ws = (char*)d_ws;
    size_t off = 0;
    auto carve = [&](size_t bytes) {
        void* p = ws + off;
        off = (off + bytes + 255) & ~(size_t)255;
        return p;
    };
    int*    H      = (int*)carve((size_t)lenH * 4);
    int*    Hs     = (int*)carve((size_t)lenH * 4);
    int*    bsum   = (int*)carve(512 * 4);
    int*    packed = (int*)carve((size_t)E * 4);
    int*    csr    = (int*)carve((size_t)E * 4);
    int*    rowptr = (int*)carve((size_t)(N + 1) * 4);
    float*  dinv   = (float*)carve((size_t)N * 4);
    __half* Wf2    = (__half*)carve(4096 * 2);
    __half* Wf3    = (__half*)carve(4096 * 2);
    float*  gsum   = (float*)carve((size_t)NGRAPHS * HID * 4);
    __half* bufH   = (__half*)carve((size_t)(N + 64) * HID * 2);  // +pad rows
    __half* bufB   = (__half*)carve((size_t)(N + 64) * HID * 2);

    const int nb_agg = (N + 15) / 16;      // 6250
    float* partv = (float*)carve((size_t)nb_agg * 128 * 4);
    int*   partg = (int*)carve((size_t)nb_agg * 2 * 4);

    // ---- CSR build (LDS counting sort, 3-pass scan pipeline)
    k_hist<<<nchunk, 256, 0, stream>>>(dst, W2, W3, Wf2, Wf3, H, gsum,
                                       E, nbkt, nchunk);
    k_scan<<<nscan, 256, 0, stream>>>(H, Hs, bsum, lenH);
    k_scatter<<<nchunk, 256, 0, stream>>>(src, dst, Hs, bsum, packed,
                                          E, nbkt, nchunk, nscan);
    // csr_build now also runs the layer-1 gemm tail for its own 512 nodes
    k_csr_build<<<nbkt, 256, 0, stream>>>(packed, Hs, bsum, rowptr, dinv, csr,
                                          x, W1, bufH,
                                          E, N, nbkt, nchunk, nscan);

    // ---- fused agg+gemm x2; layer-3 agg -> partials
    k_agg_gemm<<<nb_agg, 256, 0, stream>>>(rowptr, csr, bufH, b1, dinv, Wf2, bufB, N);
    k_agg_gemm<<<nb_agg, 256, 0, stream>>>(rowptr, csr, bufB, b2, dinv, Wf3, bufH, N);
    k_agg_part<<<nb_agg, 256, 0, stream>>>(rowptr, csr, bufH, b3, dinv, batch,
                                           partv, partg, gsum, N);

    // ---- mean-pool over partials + head (one block per graph)
    k_pool_head<<<NGRAPHS, 256, 0, stream>>>(partv, partg, gsum, batch,
                                             Wl, bl, out, N);
}

// Round 4
// 222.750 us; speedup vs baseline: 1.1153x; 1.1153x over previous
//
#include <hip/hip_runtime.h>
#include <hip/hip_fp16.h>

#define HID 64
#define NGRAPHS 256
#define CHUNK 4096        // edges per pass-1 chunk (306 blocks > 256 CUs)
#define BKTSZ 512         // nodes per coarse bucket
#define BKTSH 9
#define PSH 17            // src fits in 17 bits (N <= 131072)
#define PMASK 0x1FFFF

typedef _Float16 half8 __attribute__((ext_vector_type(8)));
typedef float f32x4 __attribute__((ext_vector_type(4)));

// MEASURED LAWS (R1-R22):
//  - scattered device-scope atomics/stores write through ~64B lines at
//    ~0.9 TB/s; same-line fp32 atomics ~15 G/s -> LDS counting-sort CSR.
//  - R13: grid.sync() ~100us at full grid -> discrete launches win.
//  - R14 (re-confirmed by R21!): narrow-grid fusion serializes wide
//    phases. gemm7 fused into 196-block csr_build: 7us -> 46us at 6.6%
//    occupancy. R17: same-grid fusion (agg+gemm) wins.
//  - R15: >8-wide gather unroll regresses. R18: keep 3-pass scan CSR.
//  - R19 DISASTER: device-scope atomics+fences poison L2 gather
//    throughput (4x). R20: per-block partials + tiny pool launch.
//  - R21 win kept: cooperative csr loads (1 coalesced load + shfl
//    broadcast) saved ~20us over serialized uniform loads.
// R22: LINEARITY. conv1 = b1 + dinv[d]*(sum_s dinv[s]x[s])@W1 -> pass 1
//    aggregates 32B x~ rows (fp32, padded 7->8) instead of 128B h1 rows
//    (4x traffic), then per-node 7->64 matvec via shfl + W2 MFMA. gemm7
//    deleted; csr_build gets a TINY x~=x*dinv tail (per-node local).

// ---- P0: prepW (blocks 0-1) + per-chunk coarse histogram ----------------

__global__ __launch_bounds__(256) void k_hist(
        const int* __restrict__ dst, const float* __restrict__ W2,
        const float* __restrict__ W3, __half* __restrict__ Wf2,
        __half* __restrict__ Wf3, int* __restrict__ H,
        float* __restrict__ gsum, int e, int nbkt, int nchunk) {
    __shared__ int cnt4[4][256];    // per-wave split: 4x less contention
    const int t = threadIdx.x, b = blockIdx.x;
    const int gtid = b * 256 + t;
    if (gtid < 512) {       // W fragment repack: 16x16x32-f16 B layout
        int p = gtid;
        int kt = p >> 8, c = (p >> 6) & 3, lane = p & 63;
        int quad = lane >> 4, m = lane & 15;
#pragma unroll
        for (int j = 0; j < 8; ++j) {
            int k = kt * 32 + quad * 8 + j;
            int ch = c * 16 + m;
            Wf2[(size_t)p * 8 + j] = __float2half(W2[k * HID + ch]);
            Wf3[(size_t)p * 8 + j] = __float2half(W3[k * HID + ch]);
        }
    }
    if (b == 0) {           // zero the (rare-case) pool spill accumulator
        for (int i = t; i < NGRAPHS * HID; i += 256) gsum[i] = 0.0f;
    }
    for (int i = t; i < 1024; i += 256) ((int*)cnt4)[i] = 0;
    __syncthreads();
    const int w = t >> 6;
#pragma unroll
    for (int it = 0; it < CHUNK / 1024; ++it) {
        int idx = b * CHUNK + it * 1024 + t * 4;
        if (idx + 3 < e) {
            int4 d = *(const int4*)(dst + idx);
            atomicAdd(&cnt4[w][d.x >> BKTSH], 1);
            atomicAdd(&cnt4[w][d.y >> BKTSH], 1);
            atomicAdd(&cnt4[w][d.z >> BKTSH], 1);
            atomicAdd(&cnt4[w][d.w >> BKTSH], 1);
        } else {
            for (int i = idx; i < e && i < idx + 4; ++i)
                atomicAdd(&cnt4[w][dst[i] >> BKTSH], 1);
        }
    }
    __syncthreads();
    for (int i = t; i < nbkt; i += 256)
        H[i * nchunk + b] = cnt4[0][i] + cnt4[1][i] + cnt4[2][i] + cnt4[3][i];
}

// ---- P1: per-1024 partial exclusive scans + block sums ------------------

__global__ __launch_bounds__(256) void k_scan(const int* __restrict__ in,
                                              int* __restrict__ outp,
                                              int* __restrict__ bsum, int n) {
    __shared__ int sh[256];
    const int t = threadIdx.x;
    const int base = blockIdx.x * 1024 + t * 4;
    int v[4];
    int s = 0;
#pragma unroll
    for (int k = 0; k < 4; k++) {
        int i = base + k;
        v[k] = (i < n) ? in[i] : 0;
        s += v[k];
    }
    sh[t] = s;
    __syncthreads();
#pragma unroll
    for (int off = 1; off < 256; off <<= 1) {
        int add = (t >= off) ? sh[t - off] : 0;
        __syncthreads();
        sh[t] += add;
        __syncthreads();
    }
    int run = sh[t] - s;
#pragma unroll
    for (int k = 0; k < 4; k++) {
        int i = base + k;
        if (i < n) outp[i] = run;
        run += v[k];
    }
    if (t == 255) bsum[blockIdx.x] = sh[255];
}

// ---- P2: bucket scatter (packed 4B, coalesced runs) ---------------------

__global__ __launch_bounds__(256) void k_scatter(
        const int* __restrict__ src, const int* __restrict__ dst,
        const int* __restrict__ Hs, const int* __restrict__ bsum,
        int* __restrict__ packed, int e, int nbkt, int nchunk, int nscan) {
    __shared__ int off[256];
    __shared__ int lc[256];
    __shared__ int bscan[64];
    const int t = threadIdx.x, b = blockIdx.x;
    if (t < 64) bscan[t] = (t < nscan) ? bsum[t] : 0;
    __syncthreads();
#pragma unroll
    for (int o = 1; o < 64; o <<= 1) {
        int add = (t < 64 && t >= o) ? bscan[t - o] : 0;
        __syncthreads();
        if (t < 64) bscan[t] += add;
        __syncthreads();
    }
    for (int i = t; i < nbkt; i += 256) {
        int idx = i * nchunk + b;
        int q = idx >> 10;
        off[i] = Hs[idx] + (q ? bscan[q - 1] : 0);
        lc[i] = 0;
    }
    __syncthreads();
#pragma unroll
    for (int it = 0; it < CHUNK / 1024; ++it) {
        int idx = b * CHUNK + it * 1024 + t * 4;
        if (idx + 3 < e) {
            int4 d = *(const int4*)(dst + idx);
            int4 s = *(const int4*)(src + idx);
            int b0 = d.x >> BKTSH, b1 = d.y >> BKTSH;
            int b2 = d.z >> BKTSH, b3 = d.w >> BKTSH;
            int r0 = atomicAdd(&lc[b0], 1);
            int r1 = atomicAdd(&lc[b1], 1);
            int r2 = atomicAdd(&lc[b2], 1);
            int r3 = atomicAdd(&lc[b3], 1);
            packed[off[b0] + r0] = s.x | ((d.x & (BKTSZ - 1)) << PSH);
            packed[off[b1] + r1] = s.y | ((d.y & (BKTSZ - 1)) << PSH);
            packed[off[b2] + r2] = s.z | ((d.z & (BKTSZ - 1)) << PSH);
            packed[off[b3] + r3] = s.w | ((d.w & (BKTSZ - 1)) << PSH);
        } else {
            for (int i = idx; i < e && i < idx + 4; ++i) {
                int dd = dst[i];
                int bk = dd >> BKTSH;
                int r = atomicAdd(&lc[bk], 1);
                packed[off[bk] + r] = src[i] | ((dd & (BKTSZ - 1)) << PSH);
            }
        }
    }
}

// ---- P3: per-bucket local CSR build + tiny x~ = x*dinv tail (R22) -------
// Tail is per-node LOCAL (512 rows * 32B write) -- not a wide phase, so
// the R14/R21 narrow-grid trap does not apply.

__global__ __launch_bounds__(256) void k_csr_build(
        const int* __restrict__ packed, const int* __restrict__ Hs,
        const int* __restrict__ bsum, int* __restrict__ rowptr,
        float* __restrict__ dinv, int* __restrict__ csr,
        const float* __restrict__ x, float* __restrict__ xt,
        int e, int n, int nbkt, int nchunk, int nscan) {
    __shared__ int cnt[BKTSZ];
    __shared__ int pref[BKTSZ];
    __shared__ int ssum[256];
    __shared__ int cnt2[BKTSZ];
    __shared__ int bscan[64];
    const int t = threadIdx.x, bkt = blockIdx.x;
    if (t < 64) bscan[t] = (t < nscan) ? bsum[t] : 0;
    if (bkt == 0 && t == 0) rowptr[n] = e;
    cnt[t] = 0; cnt[t + 256] = 0;
    cnt2[t] = 0; cnt2[t + 256] = 0;
    __syncthreads();
#pragma unroll
    for (int o = 1; o < 64; o <<= 1) {
        int add = (t < 64 && t >= o) ? bscan[t - o] : 0;
        __syncthreads();
        if (t < 64) bscan[t] += add;
        __syncthreads();
    }
    int i0 = bkt * nchunk;
    int q0 = i0 >> 10;
    int segStart = Hs[i0] + (q0 ? bscan[q0 - 1] : 0);
    int segEnd = e;
    if (bkt + 1 < nbkt) {
        int i1 = (bkt + 1) * nchunk;
        int q1 = i1 >> 10;
        segEnd = Hs[i1] + (q1 ? bscan[q1 - 1] : 0);
    }
    for (int j = segStart + t; j < segEnd; j += 256)
        atomicAdd(&cnt[(packed[j] >> PSH) & (BKTSZ - 1)], 1);
    __syncthreads();
    int a0 = cnt[2 * t], a1 = cnt[2 * t + 1];
    int s = a0 + a1;
    ssum[t] = s;
    __syncthreads();
#pragma unroll
    for (int off = 1; off < 256; off <<= 1) {
        int add = (t >= off) ? ssum[t - off] : 0;
        __syncthreads();
        ssum[t] += add;
        __syncthreads();
    }
    int p = ssum[t] - s;
    pref[2 * t] = p;
    pref[2 * t + 1] = p + a0;
    __syncthreads();
    for (int i = t; i < BKTSZ; i += 256) {
        int node = bkt * BKTSZ + i;
        if (node < n) {
            rowptr[node] = segStart + pref[i];
            dinv[node] = rsqrtf((float)(cnt[i] + 1));   // +1 self-loop
        }
    }
    for (int j = segStart + t; j < segEnd; j += 256) {
        int pk = packed[j];
        int ld = (pk >> PSH) & (BKTSZ - 1);
        int r = atomicAdd(&cnt2[ld], 1);
        csr[segStart + pref[ld] + r] = pk & PMASK;
    }
    // ---- tail: x~[node] = x[node] * dinv[node], padded to 8 floats
    for (int i = t; i < BKTSZ * 8; i += 256) {
        int nl = i >> 3, k = i & 7;
        int node = bkt * BKTSZ + nl;
        if (node < n)
            xt[(size_t)node * 8 + k] =
                (k < 7) ? x[(size_t)node * 7 + k] * rsqrtf((float)(cnt[nl] + 1))
                        : 0.0f;
    }
}

__device__ __forceinline__ float4 h4_to_f4(int2 raw) {
    __half2 p0 = *(__half2*)&raw.x;
    __half2 p1 = *(__half2*)&raw.y;
    float2 f0 = __half22float2(p0);
    float2 f1 = __half22float2(p1);
    return make_float4(f0.x, f0.y, f1.x, f1.y);
}

// ---- FUSED layers 1+2: aggregate x~ (32B rows) + W1 matvec + W2 MFMA ----
// Lane l16 accumulates component (l16&7); lanes 0-7 take even edge slots,
// 8-15 odd. shfl_xor(8) combines, 7 shfl broadcasts distribute agg7 to
// all 16 lanes for the per-lane 4-channel W1 matvec. Then relu, stage,
// MFMA with Wf2, *dinv -> h2' (identical epilogue to k_agg_gemm).

__global__ __launch_bounds__(256) void k_aggx_gemm(
        const int* __restrict__ rowptr, const int* __restrict__ csr,
        const float* __restrict__ xt, const float* __restrict__ b,
        const float* __restrict__ dinv, const float* __restrict__ W1,
        const __half* __restrict__ Wf, __half* __restrict__ hout,
        int n_nodes) {
    __shared__ __half act[16 * 72];
    __shared__ float W1s[7 * HID];
    const int t = threadIdx.x;
    const int n0 = blockIdx.x * 16;
    const int nl = t >> 4;          // local node 0..15
    const int node = n0 + nl;
    const int l16 = t & 15;
    const int c8 = l16 & 7;         // my x~ component
    const float4* b4 = (const float4*)b;

    for (int i = t; i < 7 * HID; i += 256) W1s[i] = W1[i];

    float4 av = make_float4(0.0f, 0.0f, 0.0f, 0.0f);
    if (node < n_nodes) {
        int beg = rowptr[node], end = rowptr[node + 1];
        float dv = dinv[node];
        // self term: only lower half adds (upper half would double count)
        float inner = (l16 < 8) ? xt[(size_t)node * 8 + c8] : 0.0f;
        int j = beg;
        for (; j + 7 < end; j += 8) {      // 8 edges: 1 csr load + 4 gathers
            int e8 = csr[j + c8];
            int sid[4];
#pragma unroll
            for (int q = 0; q < 4; ++q)
                sid[q] = __shfl(e8, 2 * q + (l16 >> 3), 8);
            float r[4];
#pragma unroll
            for (int q = 0; q < 4; ++q)
                r[q] = xt[(size_t)sid[q] * 8 + c8];
#pragma unroll
            for (int q = 0; q < 4; ++q) inner += r[q];
        }
        if (j + 3 < end) {                 // 4 edges: 2 gathers
            int e4 = csr[j + (l16 & 3)];
            int sid[2];
#pragma unroll
            for (int q = 0; q < 2; ++q)
                sid[q] = __shfl(e4, 2 * q + (l16 >> 3), 4);
            float r[2];
#pragma unroll
            for (int q = 0; q < 2; ++q)
                r[q] = xt[(size_t)sid[q] * 8 + c8];
            inner += r[0] + r[1];
            j += 4;
        }
        for (; j < end; ++j)               // <=3 edges, lower half only
            if (l16 < 8) inner += xt[(size_t)csr[j] * 8 + c8];

        inner += __shfl_xor(inner, 8, 16); // combine halves
        float agg[7];
#pragma unroll
        for (int k = 0; k < 7; ++k) agg[k] = __shfl(inner, k, 16);

        float4 bb = b4[l16];
#pragma unroll
        for (int i = 0; i < 4; ++i) {
            int c = l16 * 4 + i;
            float dot = 0.0f;
#pragma unroll
            for (int k = 0; k < 7; ++k) dot += agg[k] * W1s[k * HID + c];
            float v = ((const float*)&bb)[i] + dv * dot;
            ((float*)&av)[i] = fmaxf(v, 0.0f);     // relu -> gemm input
        }
    }
    {   // stage act tile: row nl, cols l16*4..+3 (8B store)
        __half2 p0 = __floats2half2_rn(av.x, av.y);
        __half2 p1 = __floats2half2_rn(av.z, av.w);
        int2 pk;
        pk.x = *(int*)&p0;
        pk.y = *(int*)&p1;
        *(int2*)&act[nl * 72 + l16 * 4] = pk;
    }
    __syncthreads();

    const int wave = t >> 6, lane = t & 63;
    const int quad = lane >> 4, m = lane & 15;
    const half8* Wf8 = (const half8*)Wf;
    f32x4 acc = {0.0f, 0.0f, 0.0f, 0.0f};
#pragma unroll
    for (int kt = 0; kt < 2; ++kt) {
        half8 a = *(const half8*)&act[m * 72 + kt * 32 + quad * 8];
        half8 bv = Wf8[(kt * 4 + wave) * 64 + lane];
        acc = __builtin_amdgcn_mfma_f32_16x16x32_f16(a, bv, acc, 0, 0, 0);
    }
#pragma unroll
    for (int r = 0; r < 4; ++r) {
        int nd = n0 + quad * 4 + r;
        if (nd < n_nodes)
            hout[(size_t)nd * HID + wave * 16 + m] =
                __float2half(acc[r] * dinv[nd]);
    }
}

// ---- FUSED aggregate + MFMA gemm (layer 2->3) ---------------------------

__global__ __launch_bounds__(256) void k_agg_gemm(
        const int* __restrict__ rowptr, const int* __restrict__ csr,
        const __half* __restrict__ h, const float* __restrict__ b,
        const float* __restrict__ dinv, const __half* __restrict__ Wf,
        __half* __restrict__ hout, int n_nodes) {
    __shared__ __half act[16 * 72];
    const int t = threadIdx.x;
    const int n0 = blockIdx.x * 16;
    const int nl = t >> 4;          // local node 0..15
    const int node = n0 + nl;
    const int l16 = t & 15;
    const int2* h8 = (const int2*)h;
    const float4* b4 = (const float4*)b;

    float4 av = make_float4(0.0f, 0.0f, 0.0f, 0.0f);
    if (node < n_nodes) {
        int beg = rowptr[node], end = rowptr[node + 1];
        float dv = dinv[node];
        float4 inner = h4_to_f4(h8[(size_t)node * 16 + l16]);   // self h'
        int j = beg;
        for (; j + 7 < end; j += 8) {       // 1 coalesced csr load / 8 edges
            int e8 = csr[j + (l16 & 7)];
            int2 r[8];
#pragma unroll
            for (int q = 0; q < 8; ++q)
                r[q] = h8[(size_t)__shfl(e8, q, 8) * 16 + l16];
#pragma unroll
            for (int q = 0; q < 8; ++q) {
                float4 v = h4_to_f4(r[q]);
                inner.x += v.x; inner.y += v.y; inner.z += v.z; inner.w += v.w;
            }
        }
        if (j + 3 < end) {
            int e4 = csr[j + (l16 & 3)];
            int2 r[4];
#pragma unroll
            for (int q = 0; q < 4; ++q)
                r[q] = h8[(size_t)__shfl(e4, q, 4) * 16 + l16];
#pragma unroll
            for (int q = 0; q < 4; ++q) {
                float4 v = h4_to_f4(r[q]);
                inner.x += v.x; inner.y += v.y; inner.z += v.z; inner.w += v.w;
            }
            j += 4;
        }
        for (; j < end; j++) {
            float4 v = h4_to_f4(h8[(size_t)csr[j] * 16 + l16]);
            inner.x += v.x; inner.y += v.y; inner.z += v.z; inner.w += v.w;
        }
        float4 bb = b4[l16];
        av.x = fmaxf(bb.x + dv * inner.x, 0.0f);   // relu(agg) = gemm input
        av.y = fmaxf(bb.y + dv * inner.y, 0.0f);
        av.z = fmaxf(bb.z + dv * inner.z, 0.0f);
        av.w = fmaxf(bb.w + dv * inner.w, 0.0f);
    }
    {   // stage act tile: row nl, cols l16*4..+3 (8B store)
        __half2 p0 = __floats2half2_rn(av.x, av.y);
        __half2 p1 = __floats2half2_rn(av.z, av.w);
        int2 pk;
        pk.x = *(int*)&p0;
        pk.y = *(int*)&p1;
        *(int2*)&act[nl * 72 + l16 * 4] = pk;
    }
    __syncthreads();

    const int wave = t >> 6, lane = t & 63;
    const int quad = lane >> 4, m = lane & 15;
    const half8* Wf8 = (const half8*)Wf;
    f32x4 acc = {0.0f, 0.0f, 0.0f, 0.0f};
#pragma unroll
    for (int kt = 0; kt < 2; ++kt) {
        half8 a = *(const half8*)&act[m * 72 + kt * 32 + quad * 8];
        half8 bv = Wf8[(kt * 4 + wave) * 64 + lane];
        acc = __builtin_amdgcn_mfma_f32_16x16x32_f16(a, bv, acc, 0, 0, 0);
    }
#pragma unroll
    for (int r = 0; r < 4; ++r) {
        int nd = n0 + quad * 4 + r;
        if (nd < n_nodes)
            hout[(size_t)nd * HID + wave * 16 + m] =
                __float2half(acc[r] * dinv[nd]);
    }
}

// ---- layer-3 aggregate -> per-block per-graph PARTIAL sums (R20) --------

__global__ __launch_bounds__(256) void k_agg_part(
        const int* __restrict__ rowptr, const int* __restrict__ csr,
        const __half* __restrict__ h, const float* __restrict__ b,
        const float* __restrict__ dinv, const int* __restrict__ batch,
        float* __restrict__ partv, int* __restrict__ partg,
        float* __restrict__ gsum, int n_nodes) {
    __shared__ float redbuf[16][64];
    __shared__ int bg[16];
    const int t = threadIdx.x;
    const int n0 = blockIdx.x * 16;
    const int nl = t >> 4;
    const int node = n0 + nl;
    const int l16 = t & 15;
    const int2* h8 = (const int2*)h;
    const float4* b4 = (const float4*)b;

    if (t < 16) {
        int nd = n0 + t;
        bg[t] = (nd < n_nodes) ? batch[nd] : -1;
    }

    float4 res = make_float4(0.0f, 0.0f, 0.0f, 0.0f);
    if (node < n_nodes) {
        int beg = rowptr[node], end = rowptr[node + 1];
        float dv = dinv[node];
        float4 inner = h4_to_f4(h8[(size_t)node * 16 + l16]);   // self h'
        int j = beg;
        for (; j + 7 < end; j += 8) {       // 1 coalesced csr load / 8 edges
            int e8 = csr[j + (l16 & 7)];
            int2 r[8];
#pragma unroll
            for (int q = 0; q < 8; ++q)
                r[q] = h8[(size_t)__shfl(e8, q, 8) * 16 + l16];
#pragma unroll
            for (int q = 0; q < 8; ++q) {
                float4 v = h4_to_f4(r[q]);
                inner.x += v.x; inner.y += v.y; inner.z += v.z; inner.w += v.w;
            }
        }
        if (j + 3 < end) {
            int e4 = csr[j + (l16 & 3)];
            int2 r[4];
#pragma unroll
            for (int q = 0; q < 4; ++q)
                r[q] = h8[(size_t)__shfl(e4, q, 4) * 16 + l16];
#pragma unroll
            for (int q = 0; q < 4; ++q) {
                float4 v = h4_to_f4(r[q]);
                inner.x += v.x; inner.y += v.y; inner.z += v.z; inner.w += v.w;
            }
            j += 4;
        }
        for (; j < end; j++) {
            float4 v = h4_to_f4(h8[(size_t)csr[j] * 16 + l16]);
            inner.x += v.x; inner.y += v.y; inner.z += v.z; inner.w += v.w;
        }
        float4 bb = b4[l16];
        res.x = bb.x + dv * inner.x;                   // layer 3: NO relu
        res.y = bb.y + dv * inner.y;
        res.z = bb.z + dv * inner.z;
        res.w = bb.w + dv * inner.w;
    }
    *(float4*)&redbuf[nl][l16 * 4] = res;
    __syncthreads();

    if (t < 64) {           // one wave: run-length reduce 16 rows -> 2 slots
        const int c = t;
        const int g0 = bg[0];
        const int g15 = bg[15];
        float s0 = 0.0f, s1 = 0.0f;
        for (int i = 0; i < 16; ++i) {
            int g = bg[i];
            float v = redbuf[i][c];
            if (g == g0) s0 += v;
            else if (g == g15) s1 += v;
            else if (g >= 0) atomicAdd(&gsum[g * HID + c], v);  // ~never
        }
        partv[(size_t)blockIdx.x * 128 + c] = s0;
        partv[(size_t)blockIdx.x * 128 + 64 + c] = s1;
        if (c == 0) {
            partg[blockIdx.x * 2 + 0] = g0;
            partg[blockIdx.x * 2 + 1] = (g15 != g0) ? g15 : -1;
        }
    }
}

// ---- mean-pool over partials + head: one block per graph ----------------

__global__ __launch_bounds__(256) void k_pool_head(
        const float* __restrict__ partv, const int* __restrict__ partg,
        const float* __restrict__ gsum, const int* __restrict__ batch,
        const float* __restrict__ Wl, const float* __restrict__ bl,
        float* __restrict__ out, int n_nodes) {
    int g = blockIdx.x;
    int lo = 0, hi = n_nodes;
    while (lo < hi) { int m = (lo + hi) >> 1; if (batch[m] < g) lo = m + 1; else hi = m; }
    int nstart = lo;
    hi = n_nodes;
    while (lo < hi) { int m = (lo + hi) >> 1; if (batch[m] < g + 1) lo = m + 1; else hi = m; }
    int nend = lo;

    int c = threadIdx.x & 63, part = threadIdx.x >> 6;
    float acc = 0.0f;
    if (nend > nstart) {
        int b0 = nstart >> 4, b1 = (nend - 1) >> 4;
        for (int b = b0 + part; b <= b1; b += 4) {
            if (partg[b * 2 + 0] == g) acc += partv[(size_t)b * 128 + c];
            if (partg[b * 2 + 1] == g) acc += partv[(size_t)b * 128 + 64 + c];
        }
    }

    __shared__ float red[4][64];
    __shared__ float hd[128];
    red[part][c] = acc;
    __syncthreads();
    if (threadIdx.x < 64) {
        float cntf = (float)(nend - nstart);
        float pooled = (red[0][c] + red[1][c] + red[2][c] + red[3][c]
                        + gsum[g * HID + c]) / fmaxf(cntf, 1.0f);
        hd[c] = pooled * Wl[c * 2 + 0];
        hd[64 + c] = pooled * Wl[c * 2 + 1];
    }
    __syncthreads();
    if (threadIdx.x < 2) {
        float s = 0.0f;
        for (int k = 0; k < 64; k++) s += hd[threadIdx.x * 64 + k];
        out[g * 2 + threadIdx.x] = s + bl[threadIdx.x];
    }
}

// -------------------------------------------------------------------------

extern "C" void kernel_launch(void* const* d_in, const int* in_sizes, int n_in,
                              void* d_out, int out_size, void* d_ws, size_t ws_size,
                              hipStream_t stream) {
    const float* x     = (const float*)d_in[0];
    const int*   ei    = (const int*)d_in[1];
    const int*   batch = (const int*)d_in[2];
    const float* W1    = (const float*)d_in[3];
    const float* b1    = (const float*)d_in[4];
    const float* W2    = (const float*)d_in[5];
    const float* b2    = (const float*)d_in[6];
    const float* W3    = (const float*)d_in[7];
    const float* b3    = (const float*)d_in[8];
    const float* Wl    = (const float*)d_in[9];
    const float* bl    = (const float*)d_in[10];
    float* out = (float*)d_out;

    const int N = in_sizes[0] / 7;     // 100000
    const int E = in_sizes[1] / 2;     // 1250000
    const int* src = ei;
    const int* dst = ei + E;

    const int nbkt   = (N + BKTSZ - 1) >> BKTSH;          // 196
    const int nchunk = (E + CHUNK - 1) / CHUNK;           // 306
    const int lenH   = nbkt * nchunk;
    const int nscan  = (lenH + 1023) / 1024;              // 59 (<=64)

    char* ws = (char*)d_ws;
    size_t off = 0;
    auto carve = [&](size_t bytes) {
        void* p = ws + off;
        off = (off + bytes + 255) & ~(size_t)255;
        return p;
    };
    int*    H      = (int*)carve((size_t)lenH * 4);
    int*    Hs     = (int*)carve((size_t)lenH * 4);
    int*    bsum   = (int*)carve(512 * 4);
    int*    packed = (int*)carve((size_t)E * 4);
    int*    csr    = (int*)carve((size_t)E * 4);
    int*    rowptr = (int*)carve((size_t)(N + 1) * 4);
    float*  dinv   = (float*)carve((size_t)N * 4);
    __half* Wf2    = (__half*)carve(4096 * 2);
    __half* Wf3    = (__half*)carve(4096 * 2);
    float*  gsum   = (float*)carve((size_t)NGRAPHS * HID * 4);
    float*  xt     = (float*)carve((size_t)(N + 64) * 8 * 4);     // padded x~
    __half* bufH   = (__half*)carve((size_t)(N + 64) * HID * 2);  // +pad rows
    __half* bufB   = (__half*)carve((size_t)(N + 64) * HID * 2);

    const int nb_agg = (N + 15) / 16;      // 6250
    float* partv = (float*)carve((size_t)nb_agg * 128 * 4);
    int*   partg = (int*)carve((size_t)nb_agg * 2 * 4);

    // ---- CSR build (LDS counting sort, 3-pass scan pipeline)
    k_hist<<<nchunk, 256, 0, stream>>>(dst, W2, W3, Wf2, Wf3, H, gsum,
                                       E, nbkt, nchunk);
    k_scan<<<nscan, 256, 0, stream>>>(H, Hs, bsum, lenH);
    k_scatter<<<nchunk, 256, 0, stream>>>(src, dst, Hs, bsum, packed,
                                          E, nbkt, nchunk, nscan);
    // csr_build also emits x~ = x*dinv (padded 8-float rows)
    k_csr_build<<<nbkt, 256, 0, stream>>>(packed, Hs, bsum, rowptr, dinv, csr,
                                          x, xt, E, N, nbkt, nchunk, nscan);

    // ---- fused layers 1+2 (x~ agg + W1 matvec + W2 MFMA); layer 2->3;
    //      layer-3 agg -> partials
    k_aggx_gemm<<<nb_agg, 256, 0, stream>>>(rowptr, csr, xt, b1, dinv, W1,
                                            Wf2, bufB, N);
    k_agg_gemm<<<nb_agg, 256, 0, stream>>>(rowptr, csr, bufB, b2, dinv, Wf3, bufH, N);
    k_agg_part<<<nb_agg, 256, 0, stream>>>(rowptr, csr, bufH, b3, dinv, batch,
                                           partv, partg, gsum, N);

    // ---- mean-pool over partials + head (one block per graph)
    k_pool_head<<<NGRAPHS, 256, 0, stream>>>(partv, partg, gsum, batch,
                                             Wl, bl, out, N);
}

// Round 5
// 196.786 us; speedup vs baseline: 1.2624x; 1.1319x over previous
//
#include <hip/hip_runtime.h>
#include <hip/hip_fp16.h>

#define HID 64
#define NGRAPHS 256
#define CHUNK 4096        // edges per pass-1 chunk (306 blocks > 256 CUs)
#define BKTSZ 512         // nodes per coarse bucket
#define BKTSH 9
#define PSH 17            // src fits in 17 bits (N <= 131072)
#define PMASK 0x1FFFF

typedef _Float16 half8 __attribute__((ext_vector_type(8)));
typedef float f32x4 __attribute__((ext_vector_type(4)));

// MEASURED LAWS (R1-R23):
//  - scattered device-scope atomics/stores ~0.9 TB/s; same-line fp32
//    atomics ~15 G/s -> LDS counting-sort CSR.
//  - R13: grid.sync() ~100us at full grid -> discrete launches win.
//  - R14/R21: narrow-grid fusion serializes wide phases (gemm7 into
//    196-block csr_build: 7->46us). R17: same-grid fusion wins.
//  - R15: >8-wide gather unroll regresses. R18: keep 3-pass scan CSR.
//  - R19 DISASTER: device-scope atomics+fences poison L2 gather
//    throughput (4x). R20: per-block partials + tiny pool launch.
//  - R21: cooperative csr loads (coalesced + shfl broadcast) ~-20us.
//  - R22: LINEARITY pass 1: aggregate 32B x~ rows, W1 matvec via shfl;
//    gemm7 deleted. 223us.
// R23: LINEARITY pass 3: everything after relu2 is linear ->
//    out[g] = b3@Wl + bl + mean_g(dinv_d * sum_s z[s]),
//    z[s] = dinv_s*(relu2[s] @ (W3@Wl)), W3@Wl is 64x2 (precomputed in
//    k_hist). Pass 2 loses the MFMA + 12.8MB write (z epilogue = 4 FMA +
//    shfl tree, 8B/node); pass 3 gathers 8B float2 rows (16x less, L2-
//    resident) with 16-edge-parallel lanes (1 gather instr / 16 edges).

// ---- P0: prepW + W3l=W3@Wl (block 0) + per-chunk coarse histogram ------

__global__ __launch_bounds__(256) void k_hist(
        const int* __restrict__ dst, const float* __restrict__ W2,
        const float* __restrict__ W3, const float* __restrict__ Wl,
        __half* __restrict__ Wf2, float* __restrict__ W3l,
        int* __restrict__ H, float* __restrict__ gsum,
        int e, int nbkt, int nchunk) {
    __shared__ int cnt4[4][256];    // per-wave split: 4x less contention
    const int t = threadIdx.x, b = blockIdx.x;
    const int gtid = b * 256 + t;
    if (gtid < 512) {       // W2 fragment repack: 16x16x32-f16 B layout
        int p = gtid;
        int kt = p >> 8, c = (p >> 6) & 3, lane = p & 63;
        int quad = lane >> 4, m = lane & 15;
#pragma unroll
        for (int j = 0; j < 8; ++j) {
            int k = kt * 32 + quad * 8 + j;
            int ch = c * 16 + m;
            Wf2[(size_t)p * 8 + j] = __float2half(W2[k * HID + ch]);
        }
    }
    if (b == 0) {
        for (int i = t; i < NGRAPHS * 2; i += 256) gsum[i] = 0.0f;
        if (t < 128) {      // W3l[j][o] = sum_k W3[j][k]*Wl[k][o]
            int j = t >> 1, o = t & 1;
            float s = 0.0f;
#pragma unroll
            for (int k = 0; k < HID; ++k) s += W3[j * HID + k] * Wl[k * 2 + o];
            W3l[j * 2 + o] = s;
        }
    }
    for (int i = t; i < 1024; i += 256) ((int*)cnt4)[i] = 0;
    __syncthreads();
    const int w = t >> 6;
#pragma unroll
    for (int it = 0; it < CHUNK / 1024; ++it) {
        int idx = b * CHUNK + it * 1024 + t * 4;
        if (idx + 3 < e) {
            int4 d = *(const int4*)(dst + idx);
            atomicAdd(&cnt4[w][d.x >> BKTSH], 1);
            atomicAdd(&cnt4[w][d.y >> BKTSH], 1);
            atomicAdd(&cnt4[w][d.z >> BKTSH], 1);
            atomicAdd(&cnt4[w][d.w >> BKTSH], 1);
        } else {
            for (int i = idx; i < e && i < idx + 4; ++i)
                atomicAdd(&cnt4[w][dst[i] >> BKTSH], 1);
        }
    }
    __syncthreads();
    for (int i = t; i < nbkt; i += 256)
        H[i * nchunk + b] = cnt4[0][i] + cnt4[1][i] + cnt4[2][i] + cnt4[3][i];
}

// ---- P1: per-1024 partial exclusive scans + block sums ------------------

__global__ __launch_bounds__(256) void k_scan(const int* __restrict__ in,
                                              int* __restrict__ outp,
                                              int* __restrict__ bsum, int n) {
    __shared__ int sh[256];
    const int t = threadIdx.x;
    const int base = blockIdx.x * 1024 + t * 4;
    int v[4];
    int s = 0;
#pragma unroll
    for (int k = 0; k < 4; k++) {
        int i = base + k;
        v[k] = (i < n) ? in[i] : 0;
        s += v[k];
    }
    sh[t] = s;
    __syncthreads();
#pragma unroll
    for (int off = 1; off < 256; off <<= 1) {
        int add = (t >= off) ? sh[t - off] : 0;
        __syncthreads();
        sh[t] += add;
        __syncthreads();
    }
    int run = sh[t] - s;
#pragma unroll
    for (int k = 0; k < 4; k++) {
        int i = base + k;
        if (i < n) outp[i] = run;
        run += v[k];
    }
    if (t == 255) bsum[blockIdx.x] = sh[255];
}

// ---- P2: bucket scatter (packed 4B, coalesced runs) ---------------------

__global__ __launch_bounds__(256) void k_scatter(
        const int* __restrict__ src, const int* __restrict__ dst,
        const int* __restrict__ Hs, const int* __restrict__ bsum,
        int* __restrict__ packed, int e, int nbkt, int nchunk, int nscan) {
    __shared__ int off[256];
    __shared__ int lc[256];
    __shared__ int bscan[64];
    const int t = threadIdx.x, b = blockIdx.x;
    if (t < 64) bscan[t] = (t < nscan) ? bsum[t] : 0;
    __syncthreads();
#pragma unroll
    for (int o = 1; o < 64; o <<= 1) {
        int add = (t < 64 && t >= o) ? bscan[t - o] : 0;
        __syncthreads();
        if (t < 64) bscan[t] += add;
        __syncthreads();
    }
    for (int i = t; i < nbkt; i += 256) {
        int idx = i * nchunk + b;
        int q = idx >> 10;
        off[i] = Hs[idx] + (q ? bscan[q - 1] : 0);
        lc[i] = 0;
    }
    __syncthreads();
#pragma unroll
    for (int it = 0; it < CHUNK / 1024; ++it) {
        int idx = b * CHUNK + it * 1024 + t * 4;
        if (idx + 3 < e) {
            int4 d = *(const int4*)(dst + idx);
            int4 s = *(const int4*)(src + idx);
            int b0 = d.x >> BKTSH, b1 = d.y >> BKTSH;
            int b2 = d.z >> BKTSH, b3 = d.w >> BKTSH;
            int r0 = atomicAdd(&lc[b0], 1);
            int r1 = atomicAdd(&lc[b1], 1);
            int r2 = atomicAdd(&lc[b2], 1);
            int r3 = atomicAdd(&lc[b3], 1);
            packed[off[b0] + r0] = s.x | ((d.x & (BKTSZ - 1)) << PSH);
            packed[off[b1] + r1] = s.y | ((d.y & (BKTSZ - 1)) << PSH);
            packed[off[b2] + r2] = s.z | ((d.z & (BKTSZ - 1)) << PSH);
            packed[off[b3] + r3] = s.w | ((d.w & (BKTSZ - 1)) << PSH);
        } else {
            for (int i = idx; i < e && i < idx + 4; ++i) {
                int dd = dst[i];
                int bk = dd >> BKTSH;
                int r = atomicAdd(&lc[bk], 1);
                packed[off[bk] + r] = src[i] | ((dd & (BKTSZ - 1)) << PSH);
            }
        }
    }
}

// ---- P3: per-bucket local CSR build + tiny x~ = x*dinv tail (R22) -------

__global__ __launch_bounds__(256) void k_csr_build(
        const int* __restrict__ packed, const int* __restrict__ Hs,
        const int* __restrict__ bsum, int* __restrict__ rowptr,
        float* __restrict__ dinv, int* __restrict__ csr,
        const float* __restrict__ x, float* __restrict__ xt,
        int e, int n, int nbkt, int nchunk, int nscan) {
    __shared__ int cnt[BKTSZ];
    __shared__ int pref[BKTSZ];
    __shared__ int ssum[256];
    __shared__ int cnt2[BKTSZ];
    __shared__ int bscan[64];
    const int t = threadIdx.x, bkt = blockIdx.x;
    if (t < 64) bscan[t] = (t < nscan) ? bsum[t] : 0;
    if (bkt == 0 && t == 0) rowptr[n] = e;
    cnt[t] = 0; cnt[t + 256] = 0;
    cnt2[t] = 0; cnt2[t + 256] = 0;
    __syncthreads();
#pragma unroll
    for (int o = 1; o < 64; o <<= 1) {
        int add = (t < 64 && t >= o) ? bscan[t - o] : 0;
        __syncthreads();
        if (t < 64) bscan[t] += add;
        __syncthreads();
    }
    int i0 = bkt * nchunk;
    int q0 = i0 >> 10;
    int segStart = Hs[i0] + (q0 ? bscan[q0 - 1] : 0);
    int segEnd = e;
    if (bkt + 1 < nbkt) {
        int i1 = (bkt + 1) * nchunk;
        int q1 = i1 >> 10;
        segEnd = Hs[i1] + (q1 ? bscan[q1 - 1] : 0);
    }
    for (int j = segStart + t; j < segEnd; j += 256)
        atomicAdd(&cnt[(packed[j] >> PSH) & (BKTSZ - 1)], 1);
    __syncthreads();
    int a0 = cnt[2 * t], a1 = cnt[2 * t + 1];
    int s = a0 + a1;
    ssum[t] = s;
    __syncthreads();
#pragma unroll
    for (int off = 1; off < 256; off <<= 1) {
        int add = (t >= off) ? ssum[t - off] : 0;
        __syncthreads();
        ssum[t] += add;
        __syncthreads();
    }
    int p = ssum[t] - s;
    pref[2 * t] = p;
    pref[2 * t + 1] = p + a0;
    __syncthreads();
    for (int i = t; i < BKTSZ; i += 256) {
        int node = bkt * BKTSZ + i;
        if (node < n) {
            rowptr[node] = segStart + pref[i];
            dinv[node] = rsqrtf((float)(cnt[i] + 1));   // +1 self-loop
        }
    }
    for (int j = segStart + t; j < segEnd; j += 256) {
        int pk = packed[j];
        int ld = (pk >> PSH) & (BKTSZ - 1);
        int r = atomicAdd(&cnt2[ld], 1);
        csr[segStart + pref[ld] + r] = pk & PMASK;
    }
    // ---- tail: x~[node] = x[node] * dinv[node], padded to 8 floats
    for (int i = t; i < BKTSZ * 8; i += 256) {
        int nl = i >> 3, k = i & 7;
        int node = bkt * BKTSZ + nl;
        if (node < n)
            xt[(size_t)node * 8 + k] =
                (k < 7) ? x[(size_t)node * 7 + k] * rsqrtf((float)(cnt[nl] + 1))
                        : 0.0f;
    }
}

__device__ __forceinline__ float4 h4_to_f4(int2 raw) {
    __half2 p0 = *(__half2*)&raw.x;
    __half2 p1 = *(__half2*)&raw.y;
    float2 f0 = __half22float2(p0);
    float2 f1 = __half22float2(p1);
    return make_float4(f0.x, f0.y, f1.x, f1.y);
}

// ---- FUSED layers 1+2: aggregate x~ (32B rows) + W1 matvec + W2 MFMA ----

__global__ __launch_bounds__(256) void k_aggx_gemm(
        const int* __restrict__ rowptr, const int* __restrict__ csr,
        const float* __restrict__ xt, const float* __restrict__ b,
        const float* __restrict__ dinv, const float* __restrict__ W1,
        const __half* __restrict__ Wf, __half* __restrict__ hout,
        int n_nodes) {
    __shared__ __half act[16 * 72];
    __shared__ float W1s[7 * HID];
    const int t = threadIdx.x;
    const int n0 = blockIdx.x * 16;
    const int nl = t >> 4;          // local node 0..15
    const int node = n0 + nl;
    const int l16 = t & 15;
    const int c8 = l16 & 7;         // my x~ component
    const float4* b4 = (const float4*)b;

    for (int i = t; i < 7 * HID; i += 256) W1s[i] = W1[i];

    float4 av = make_float4(0.0f, 0.0f, 0.0f, 0.0f);
    if (node < n_nodes) {
        int beg = rowptr[node], end = rowptr[node + 1];
        float dv = dinv[node];
        // self term: only lower half adds (upper half would double count)
        float inner = (l16 < 8) ? xt[(size_t)node * 8 + c8] : 0.0f;
        int j = beg;
        for (; j + 7 < end; j += 8) {      // 8 edges: 1 csr load + 4 gathers
            int e8 = csr[j + c8];
            int sid[4];
#pragma unroll
            for (int q = 0; q < 4; ++q)
                sid[q] = __shfl(e8, 2 * q + (l16 >> 3), 8);
            float r[4];
#pragma unroll
            for (int q = 0; q < 4; ++q)
                r[q] = xt[(size_t)sid[q] * 8 + c8];
#pragma unroll
            for (int q = 0; q < 4; ++q) inner += r[q];
        }
        if (j + 3 < end) {                 // 4 edges: 2 gathers
            int e4 = csr[j + (l16 & 3)];
            int sid[2];
#pragma unroll
            for (int q = 0; q < 2; ++q)
                sid[q] = __shfl(e4, 2 * q + (l16 >> 3), 4);
            float r[2];
#pragma unroll
            for (int q = 0; q < 2; ++q)
                r[q] = xt[(size_t)sid[q] * 8 + c8];
            inner += r[0] + r[1];
            j += 4;
        }
        for (; j < end; ++j)               // <=3 edges, lower half only
            if (l16 < 8) inner += xt[(size_t)csr[j] * 8 + c8];

        inner += __shfl_xor(inner, 8, 16); // combine halves
        float agg[7];
#pragma unroll
        for (int k = 0; k < 7; ++k) agg[k] = __shfl(inner, k, 16);

        float4 bb = b4[l16];
#pragma unroll
        for (int i = 0; i < 4; ++i) {
            int c = l16 * 4 + i;
            float dot = 0.0f;
#pragma unroll
            for (int k = 0; k < 7; ++k) dot += agg[k] * W1s[k * HID + c];
            float v = ((const float*)&bb)[i] + dv * dot;
            ((float*)&av)[i] = fmaxf(v, 0.0f);     // relu -> gemm input
        }
    }
    {   // stage act tile: row nl, cols l16*4..+3 (8B store)
        __half2 p0 = __floats2half2_rn(av.x, av.y);
        __half2 p1 = __floats2half2_rn(av.z, av.w);
        int2 pk;
        pk.x = *(int*)&p0;
        pk.y = *(int*)&p1;
        *(int2*)&act[nl * 72 + l16 * 4] = pk;
    }
    __syncthreads();

    const int wave = t >> 6, lane = t & 63;
    const int quad = lane >> 4, m = lane & 15;
    const half8* Wf8 = (const half8*)Wf;
    f32x4 acc = {0.0f, 0.0f, 0.0f, 0.0f};
#pragma unroll
    for (int kt = 0; kt < 2; ++kt) {
        half8 a = *(const half8*)&act[m * 72 + kt * 32 + quad * 8];
        half8 bv = Wf8[(kt * 4 + wave) * 64 + lane];
        acc = __builtin_amdgcn_mfma_f32_16x16x32_f16(a, bv, acc, 0, 0, 0);
    }
#pragma unroll
    for (int r = 0; r < 4; ++r) {
        int nd = n0 + quad * 4 + r;
        if (nd < n_nodes)
            hout[(size_t)nd * HID + wave * 16 + m] =
                __float2half(acc[r] * dinv[nd]);
    }
}

// ---- pass 2 (R23): aggregate h2-msgs + relu2 + z = dinv*(relu2@W3l) -----
// Same verified gather as k_agg_gemm; epilogue is 8 FMA + shfl tree + 8B
// write per node. No LDS, no MFMA, no 12.8MB hout.

__global__ __launch_bounds__(256) void k_agg_z(
        const int* __restrict__ rowptr, const int* __restrict__ csr,
        const __half* __restrict__ h, const float* __restrict__ b,
        const float* __restrict__ dinv, const float* __restrict__ W3l,
        float2* __restrict__ zbuf, int n_nodes) {
    const int t = threadIdx.x;
    const int n0 = blockIdx.x * 16;
    const int nl = t >> 4;          // local node 0..15
    const int node = n0 + nl;
    const int l16 = t & 15;
    const int2* h8 = (const int2*)h;
    const float4* b4 = (const float4*)b;

    float w3l0[4], w3l1[4];         // my 4 channels' W3l rows (L1-cached)
#pragma unroll
    for (int i = 0; i < 4; ++i) {
        w3l0[i] = W3l[(l16 * 4 + i) * 2 + 0];
        w3l1[i] = W3l[(l16 * 4 + i) * 2 + 1];
    }

    float4 av = make_float4(0.0f, 0.0f, 0.0f, 0.0f);
    float dv = 0.0f;
    if (node < n_nodes) {
        int beg = rowptr[node], end = rowptr[node + 1];
        dv = dinv[node];
        float4 inner = h4_to_f4(h8[(size_t)node * 16 + l16]);   // self h'
        int j = beg;
        for (; j + 7 < end; j += 8) {       // 1 coalesced csr load / 8 edges
            int e8 = csr[j + (l16 & 7)];
            int2 r[8];
#pragma unroll
            for (int q = 0; q < 8; ++q)
                r[q] = h8[(size_t)__shfl(e8, q, 8) * 16 + l16];
#pragma unroll
            for (int q = 0; q < 8; ++q) {
                float4 v = h4_to_f4(r[q]);
                inner.x += v.x; inner.y += v.y; inner.z += v.z; inner.w += v.w;
            }
        }
        if (j + 3 < end) {
            int e4 = csr[j + (l16 & 3)];
            int2 r[4];
#pragma unroll
            for (int q = 0; q < 4; ++q)
                r[q] = h8[(size_t)__shfl(e4, q, 4) * 16 + l16];
#pragma unroll
            for (int q = 0; q < 4; ++q) {
                float4 v = h4_to_f4(r[q]);
                inner.x += v.x; inner.y += v.y; inner.z += v.z; inner.w += v.w;
            }
            j += 4;
        }
        for (; j < end; j++) {
            float4 v = h4_to_f4(h8[(size_t)csr[j] * 16 + l16]);
            inner.x += v.x; inner.y += v.y; inner.z += v.z; inner.w += v.w;
        }
        float4 bb = b4[l16];
        av.x = fmaxf(bb.x + dv * inner.x, 0.0f);   // relu2
        av.y = fmaxf(bb.y + dv * inner.y, 0.0f);
        av.z = fmaxf(bb.z + dv * inner.z, 0.0f);
        av.w = fmaxf(bb.w + dv * inner.w, 0.0f);
    }
    // z = dinv * (relu2 @ W3l): per-lane 4-ch partial, 16-lane shfl tree
    float p0 = av.x * w3l0[0] + av.y * w3l0[1] + av.z * w3l0[2] + av.w * w3l0[3];
    float p1 = av.x * w3l1[0] + av.y * w3l1[1] + av.z * w3l1[2] + av.w * w3l1[3];
#pragma unroll
    for (int o = 8; o; o >>= 1) {
        p0 += __shfl_xor(p0, o, 16);
        p1 += __shfl_xor(p1, o, 16);
    }
    if (node < n_nodes && l16 == 0)
        zbuf[node] = make_float2(p0 * dv, p1 * dv);
}

// ---- pass 3 (R23): aggregate z (8B rows, L2-resident) -> graph partials -
// 16 lanes per node, each lane one EDGE: 1 coalesced csr load + 1 gather
// instruction per 16 edges. y[d] = dinv_d*(z[d]+sum z[nb]); per-block
// run-length partials (plain stores, R20 pattern).

__global__ __launch_bounds__(256) void k_zagg_part(
        const int* __restrict__ rowptr, const int* __restrict__ csr,
        const float2* __restrict__ zbuf, const float* __restrict__ dinv,
        const int* __restrict__ batch, float* __restrict__ partv,
        int* __restrict__ partg, float* __restrict__ gsum, int n_nodes) {
    __shared__ float2 ys[16];
    __shared__ int bg[16];
    const int t = threadIdx.x;
    const int n0 = blockIdx.x * 16;
    const int nl = t >> 4;
    const int node = n0 + nl;
    const int q = t & 15;

    if (t < 16) {
        int nd = n0 + t;
        bg[t] = (nd < n_nodes) ? batch[nd] : -1;
    }

    float2 yv = make_float2(0.0f, 0.0f);
    if (node < n_nodes) {
        int beg = rowptr[node], end = rowptr[node + 1];
        float2 acc = make_float2(0.0f, 0.0f);
        if (q == 0) acc = zbuf[node];          // self-loop
        int j = beg;
        for (; j + 15 < end; j += 16) {        // 16 edges/iter, 1 gather instr
            int e = csr[j + q];
            float2 v = zbuf[e];
            acc.x += v.x; acc.y += v.y;
        }
        int rem = end - j;
        if (q < rem) {
            int e = csr[j + q];
            float2 v = zbuf[e];
            acc.x += v.x; acc.y += v.y;
        }
#pragma unroll
        for (int o = 8; o; o >>= 1) {
            acc.x += __shfl_xor(acc.x, o, 16);
            acc.y += __shfl_xor(acc.y, o, 16);
        }
        float dv = dinv[node];
        yv = make_float2(acc.x * dv, acc.y * dv);
    }
    if (q == 0) ys[nl] = yv;
    __syncthreads();

    if (t == 0) {           // run-length reduce 16 nodes -> <=2 graph slots
        const int g0 = bg[0];
        const int g15 = bg[15];
        float2 s0 = make_float2(0.0f, 0.0f), s1 = make_float2(0.0f, 0.0f);
        for (int i = 0; i < 16; ++i) {
            int g = bg[i];
            float2 v = ys[i];
            if (g == g0) { s0.x += v.x; s0.y += v.y; }
            else if (g == g15) { s1.x += v.x; s1.y += v.y; }
            else if (g >= 0) {                 // ~never (graph <=14 nodes)
                atomicAdd(&gsum[g * 2 + 0], v.x);
                atomicAdd(&gsum[g * 2 + 1], v.y);
            }
        }
        partv[(size_t)blockIdx.x * 4 + 0] = s0.x;
        partv[(size_t)blockIdx.x * 4 + 1] = s0.y;
        partv[(size_t)blockIdx.x * 4 + 2] = s1.x;
        partv[(size_t)blockIdx.x * 4 + 3] = s1.y;
        partg[blockIdx.x * 2 + 0] = g0;
        partg[blockIdx.x * 2 + 1] = (g15 != g0) ? g15 : -1;
    }
}

// ---- pool over float2 partials + head bias: one block per graph ---------

__global__ __launch_bounds__(256) void k_pool_head(
        const float* __restrict__ partv, const int* __restrict__ partg,
        const float* __restrict__ gsum, const int* __restrict__ batch,
        const float* __restrict__ b3, const float* __restrict__ Wl,
        const float* __restrict__ bl, float* __restrict__ out, int n_nodes) {
    int g = blockIdx.x;
    int lo = 0, hi = n_nodes;
    while (lo < hi) { int m = (lo + hi) >> 1; if (batch[m] < g) lo = m + 1; else hi = m; }
    int nstart = lo;
    hi = n_nodes;
    while (lo < hi) { int m = (lo + hi) >> 1; if (batch[m] < g + 1) lo = m + 1; else hi = m; }
    int nend = lo;

    const int t = threadIdx.x;
    float ax = 0.0f, ay = 0.0f;
    if (nend > nstart) {
        int b0 = nstart >> 4, b1 = (nend - 1) >> 4;
        for (int b = b0 + t; b <= b1; b += 256) {
            if (partg[b * 2 + 0] == g) { ax += partv[(size_t)b * 4 + 0]; ay += partv[(size_t)b * 4 + 1]; }
            if (partg[b * 2 + 1] == g) { ax += partv[(size_t)b * 4 + 2]; ay += partv[(size_t)b * 4 + 3]; }
        }
    }
    __shared__ float rx[256], ry[256];
    rx[t] = ax; ry[t] = ay;
    __syncthreads();
    for (int s2 = 128; s2; s2 >>= 1) {
        if (t < s2) { rx[t] += rx[t + s2]; ry[t] += ry[t + s2]; }
        __syncthreads();
    }
    if (t < 2) {
        float cntf = fmaxf((float)(nend - nstart), 1.0f);
        float s = ((t == 0) ? rx[0] : ry[0]) + gsum[g * 2 + t];
        float hb = 0.0f;                     // b3 @ Wl (column t)
        for (int c = 0; c < HID; ++c) hb += b3[c] * Wl[c * 2 + t];
        out[g * 2 + t] = s / cntf + hb + bl[t];
    }
}

// -------------------------------------------------------------------------

extern "C" void kernel_launch(void* const* d_in, const int* in_sizes, int n_in,
                              void* d_out, int out_size, void* d_ws, size_t ws_size,
                              hipStream_t stream) {
    const float* x     = (const float*)d_in[0];
    const int*   ei    = (const int*)d_in[1];
    const int*   batch = (const int*)d_in[2];
    const float* W1    = (const float*)d_in[3];
    const float* b1    = (const float*)d_in[4];
    const float* W2    = (const float*)d_in[5];
    const float* b2    = (const float*)d_in[6];
    const float* W3    = (const float*)d_in[7];
    const float* b3    = (const float*)d_in[8];
    const float* Wl    = (const float*)d_in[9];
    const float* bl    = (const float*)d_in[10];
    float* out = (float*)d_out;

    const int N = in_sizes[0] / 7;     // 100000
    const int E = in_sizes[1] / 2;     // 1250000
    const int* src = ei;
    const int* dst = ei + E;

    const int nbkt   = (N + BKTSZ - 1) >> BKTSH;          // 196
    const int nchunk = (E + CHUNK - 1) / CHUNK;           // 306
    const int lenH   = nbkt * nchunk;
    const int nscan  = (lenH + 1023) / 1024;              // 59 (<=64)

    char* ws = (char*)d_ws;
    size_t off = 0;
    auto carve = [&](size_t bytes) {
        void* p = ws + off;
        off = (off + bytes + 255) & ~(size_t)255;
        return p;
    };
    int*    H      = (int*)carve((size_t)lenH * 4);
    int*    Hs     = (int*)carve((size_t)lenH * 4);
    int*    bsum   = (int*)carve(512 * 4);
    int*    packed = (int*)carve((size_t)E * 4);
    int*    csr    = (int*)carve((size_t)E * 4);
    int*    rowptr = (int*)carve((size_t)(N + 1) * 4);
    float*  dinv   = (float*)carve((size_t)N * 4);
    __half* Wf2    = (__half*)carve(4096 * 2);
    float*  W3l    = (float*)carve(128 * 4);
    float*  gsum   = (float*)carve((size_t)NGRAPHS * 2 * 4);
    float*  xt     = (float*)carve((size_t)(N + 64) * 8 * 4);     // padded x~
    __half* bufB   = (__half*)carve((size_t)(N + 64) * HID * 2);  // +pad rows
    float2* zbuf   = (float2*)carve((size_t)(N + 64) * 8);

    const int nb_agg = (N + 15) / 16;      // 6250
    float* partv = (float*)carve((size_t)nb_agg * 4 * 4);
    int*   partg = (int*)carve((size_t)nb_agg * 2 * 4);

    // ---- CSR build (LDS counting sort, 3-pass scan pipeline)
    k_hist<<<nchunk, 256, 0, stream>>>(dst, W2, W3, Wl, Wf2, W3l, H, gsum,
                                       E, nbkt, nchunk);
    k_scan<<<nscan, 256, 0, stream>>>(H, Hs, bsum, lenH);
    k_scatter<<<nchunk, 256, 0, stream>>>(src, dst, Hs, bsum, packed,
                                          E, nbkt, nchunk, nscan);
    // csr_build also emits x~ = x*dinv (padded 8-float rows)
    k_csr_build<<<nbkt, 256, 0, stream>>>(packed, Hs, bsum, rowptr, dinv, csr,
                                          x, xt, E, N, nbkt, nchunk, nscan);

    // ---- fused layers 1+2 (x~ agg + W1 matvec + W2 MFMA) -> bufB
    k_aggx_gemm<<<nb_agg, 256, 0, stream>>>(rowptr, csr, xt, b1, dinv, W1,
                                            Wf2, bufB, N);
    // ---- pass 2: agg bufB + relu2 + z = dinv*(relu2@W3l) (8B/node)
    k_agg_z<<<nb_agg, 256, 0, stream>>>(rowptr, csr, bufB, b2, dinv, W3l,
                                        zbuf, N);
    // ---- pass 3: agg z (8B rows) -> per-block graph partials
    k_zagg_part<<<nb_agg, 256, 0, stream>>>(rowptr, csr, zbuf, dinv, batch,
                                            partv, partg, gsum, N);

    // ---- pool over partials + head (one block per graph)
    k_pool_head<<<NGRAPHS, 256, 0, stream>>>(partv, partg, gsum, batch,
                                             b3, Wl, bl, out, N);
}

// Round 6
// 195.213 us; speedup vs baseline: 1.2726x; 1.0081x over previous
//
#include <hip/hip_runtime.h>
#include <hip/hip_fp16.h>

#define HID 64
#define NGRAPHS 256
#define CHUNK 4096        // edges per pass-1 chunk (306 blocks > 256 CUs)
#define BKTSZ 512         // nodes per coarse bucket
#define BKTSH 9
#define PSH 17            // src fits in 17 bits (N <= 131072)
#define PMASK 0x1FFFF

typedef _Float16 half8 __attribute__((ext_vector_type(8)));
typedef float f32x4 __attribute__((ext_vector_type(4)));

// MEASURED LAWS (R1-R24):
//  - scattered device-scope atomics/stores ~0.9 TB/s; same-line fp32
//    atomics ~15 G/s -> LDS counting-sort CSR.
//  - R13: grid.sync() ~100us at full grid -> discrete launches win.
//  - R14/R21: narrow-grid fusion serializes wide phases. R17: same-grid
//    fusion wins. R15: >8-wide gather unroll regresses.
//  - R18: keep 3-pass scan CSR. R19: device-scope atomics+fences poison
//    L2 gather throughput (4x). R20: per-block partials + tiny pool.
//  - R21: cooperative csr loads (coalesced + shfl broadcast) ~-20us.
//  - R22: LINEARITY pass 1 (aggregate 32B x~ rows, shfl W1 matvec).
//  - R23: LINEARITY tail: z=dinv*(relu2@(W3@Wl)) 8B rows; pass 2 loses
//    MFMA+12.8MB write; pass 3 gathers 8B rows. 197us.
// R24: gather passes are memory-INSTRUCTION/latency bound (VALUBusy 6%,
//    ~1.5TB/s eff): (a) aggx lane-per-edge 2xfloat4 row loads -- 4x fewer
//    gather instrs, no loop shfls; (b) agg_z dwordx4 slices -- each instr
//    reads 2 full 128B rows, 2x fewer instrs; float8 accumulators.

// ---- P0: prepW + W3l=W3@Wl (block 0) + per-chunk coarse histogram ------

__global__ __launch_bounds__(256) void k_hist(
        const int* __restrict__ dst, const float* __restrict__ W2,
        const float* __restrict__ W3, const float* __restrict__ Wl,
        __half* __restrict__ Wf2, float* __restrict__ W3l,
        int* __restrict__ H, float* __restrict__ gsum,
        int e, int nbkt, int nchunk) {
    __shared__ int cnt4[4][256];    // per-wave split: 4x less contention
    const int t = threadIdx.x, b = blockIdx.x;
    const int gtid = b * 256 + t;
    if (gtid < 512) {       // W2 fragment repack: 16x16x32-f16 B layout
        int p = gtid;
        int kt = p >> 8, c = (p >> 6) & 3, lane = p & 63;
        int quad = lane >> 4, m = lane & 15;
#pragma unroll
        for (int j = 0; j < 8; ++j) {
            int k = kt * 32 + quad * 8 + j;
            int ch = c * 16 + m;
            Wf2[(size_t)p * 8 + j] = __float2half(W2[k * HID + ch]);
        }
    }
    if (b == 0) {
        for (int i = t; i < NGRAPHS * 2; i += 256) gsum[i] = 0.0f;
        if (t < 128) {      // W3l[j][o] = sum_k W3[j][k]*Wl[k][o]
            int j = t >> 1, o = t & 1;
            float s = 0.0f;
#pragma unroll
            for (int k = 0; k < HID; ++k) s += W3[j * HID + k] * Wl[k * 2 + o];
            W3l[j * 2 + o] = s;
        }
    }
    for (int i = t; i < 1024; i += 256) ((int*)cnt4)[i] = 0;
    __syncthreads();
    const int w = t >> 6;
#pragma unroll
    for (int it = 0; it < CHUNK / 1024; ++it) {
        int idx = b * CHUNK + it * 1024 + t * 4;
        if (idx + 3 < e) {
            int4 d = *(const int4*)(dst + idx);
            atomicAdd(&cnt4[w][d.x >> BKTSH], 1);
            atomicAdd(&cnt4[w][d.y >> BKTSH], 1);
            atomicAdd(&cnt4[w][d.z >> BKTSH], 1);
            atomicAdd(&cnt4[w][d.w >> BKTSH], 1);
        } else {
            for (int i = idx; i < e && i < idx + 4; ++i)
                atomicAdd(&cnt4[w][dst[i] >> BKTSH], 1);
        }
    }
    __syncthreads();
    for (int i = t; i < nbkt; i += 256)
        H[i * nchunk + b] = cnt4[0][i] + cnt4[1][i] + cnt4[2][i] + cnt4[3][i];
}

// ---- P1: per-1024 partial exclusive scans + block sums ------------------

__global__ __launch_bounds__(256) void k_scan(const int* __restrict__ in,
                                              int* __restrict__ outp,
                                              int* __restrict__ bsum, int n) {
    __shared__ int sh[256];
    const int t = threadIdx.x;
    const int base = blockIdx.x * 1024 + t * 4;
    int v[4];
    int s = 0;
#pragma unroll
    for (int k = 0; k < 4; k++) {
        int i = base + k;
        v[k] = (i < n) ? in[i] : 0;
        s += v[k];
    }
    sh[t] = s;
    __syncthreads();
#pragma unroll
    for (int off = 1; off < 256; off <<= 1) {
        int add = (t >= off) ? sh[t - off] : 0;
        __syncthreads();
        sh[t] += add;
        __syncthreads();
    }
    int run = sh[t] - s;
#pragma unroll
    for (int k = 0; k < 4; k++) {
        int i = base + k;
        if (i < n) outp[i] = run;
        run += v[k];
    }
    if (t == 255) bsum[blockIdx.x] = sh[255];
}

// ---- P2: bucket scatter (packed 4B, coalesced runs) ---------------------

__global__ __launch_bounds__(256) void k_scatter(
        const int* __restrict__ src, const int* __restrict__ dst,
        const int* __restrict__ Hs, const int* __restrict__ bsum,
        int* __restrict__ packed, int e, int nbkt, int nchunk, int nscan) {
    __shared__ int off[256];
    __shared__ int lc[256];
    __shared__ int bscan[64];
    const int t = threadIdx.x, b = blockIdx.x;
    if (t < 64) bscan[t] = (t < nscan) ? bsum[t] : 0;
    __syncthreads();
#pragma unroll
    for (int o = 1; o < 64; o <<= 1) {
        int add = (t < 64 && t >= o) ? bscan[t - o] : 0;
        __syncthreads();
        if (t < 64) bscan[t] += add;
        __syncthreads();
    }
    for (int i = t; i < nbkt; i += 256) {
        int idx = i * nchunk + b;
        int q = idx >> 10;
        off[i] = Hs[idx] + (q ? bscan[q - 1] : 0);
        lc[i] = 0;
    }
    __syncthreads();
#pragma unroll
    for (int it = 0; it < CHUNK / 1024; ++it) {
        int idx = b * CHUNK + it * 1024 + t * 4;
        if (idx + 3 < e) {
            int4 d = *(const int4*)(dst + idx);
            int4 s = *(const int4*)(src + idx);
            int b0 = d.x >> BKTSH, b1 = d.y >> BKTSH;
            int b2 = d.z >> BKTSH, b3 = d.w >> BKTSH;
            int r0 = atomicAdd(&lc[b0], 1);
            int r1 = atomicAdd(&lc[b1], 1);
            int r2 = atomicAdd(&lc[b2], 1);
            int r3 = atomicAdd(&lc[b3], 1);
            packed[off[b0] + r0] = s.x | ((d.x & (BKTSZ - 1)) << PSH);
            packed[off[b1] + r1] = s.y | ((d.y & (BKTSZ - 1)) << PSH);
            packed[off[b2] + r2] = s.z | ((d.z & (BKTSZ - 1)) << PSH);
            packed[off[b3] + r3] = s.w | ((d.w & (BKTSZ - 1)) << PSH);
        } else {
            for (int i = idx; i < e && i < idx + 4; ++i) {
                int dd = dst[i];
                int bk = dd >> BKTSH;
                int r = atomicAdd(&lc[bk], 1);
                packed[off[bk] + r] = src[i] | ((dd & (BKTSZ - 1)) << PSH);
            }
        }
    }
}

// ---- P3: per-bucket local CSR build + tiny x~ = x*dinv tail (R22) -------

__global__ __launch_bounds__(256) void k_csr_build(
        const int* __restrict__ packed, const int* __restrict__ Hs,
        const int* __restrict__ bsum, int* __restrict__ rowptr,
        float* __restrict__ dinv, int* __restrict__ csr,
        const float* __restrict__ x, float* __restrict__ xt,
        int e, int n, int nbkt, int nchunk, int nscan) {
    __shared__ int cnt[BKTSZ];
    __shared__ int pref[BKTSZ];
    __shared__ int ssum[256];
    __shared__ int cnt2[BKTSZ];
    __shared__ int bscan[64];
    const int t = threadIdx.x, bkt = blockIdx.x;
    if (t < 64) bscan[t] = (t < nscan) ? bsum[t] : 0;
    if (bkt == 0 && t == 0) rowptr[n] = e;
    cnt[t] = 0; cnt[t + 256] = 0;
    cnt2[t] = 0; cnt2[t + 256] = 0;
    __syncthreads();
#pragma unroll
    for (int o = 1; o < 64; o <<= 1) {
        int add = (t < 64 && t >= o) ? bscan[t - o] : 0;
        __syncthreads();
        if (t < 64) bscan[t] += add;
        __syncthreads();
    }
    int i0 = bkt * nchunk;
    int q0 = i0 >> 10;
    int segStart = Hs[i0] + (q0 ? bscan[q0 - 1] : 0);
    int segEnd = e;
    if (bkt + 1 < nbkt) {
        int i1 = (bkt + 1) * nchunk;
        int q1 = i1 >> 10;
        segEnd = Hs[i1] + (q1 ? bscan[q1 - 1] : 0);
    }
    for (int j = segStart + t; j < segEnd; j += 256)
        atomicAdd(&cnt[(packed[j] >> PSH) & (BKTSZ - 1)], 1);
    __syncthreads();
    int a0 = cnt[2 * t], a1 = cnt[2 * t + 1];
    int s = a0 + a1;
    ssum[t] = s;
    __syncthreads();
#pragma unroll
    for (int off = 1; off < 256; off <<= 1) {
        int add = (t >= off) ? ssum[t - off] : 0;
        __syncthreads();
        ssum[t] += add;
        __syncthreads();
    }
    int p = ssum[t] - s;
    pref[2 * t] = p;
    pref[2 * t + 1] = p + a0;
    __syncthreads();
    for (int i = t; i < BKTSZ; i += 256) {
        int node = bkt * BKTSZ + i;
        if (node < n) {
            rowptr[node] = segStart + pref[i];
            dinv[node] = rsqrtf((float)(cnt[i] + 1));   // +1 self-loop
        }
    }
    for (int j = segStart + t; j < segEnd; j += 256) {
        int pk = packed[j];
        int ld = (pk >> PSH) & (BKTSZ - 1);
        int r = atomicAdd(&cnt2[ld], 1);
        csr[segStart + pref[ld] + r] = pk & PMASK;
    }
    // ---- tail: x~[node] = x[node] * dinv[node], padded to 8 floats
    for (int i = t; i < BKTSZ * 8; i += 256) {
        int nl = i >> 3, k = i & 7;
        int node = bkt * BKTSZ + nl;
        if (node < n)
            xt[(size_t)node * 8 + k] =
                (k < 7) ? x[(size_t)node * 7 + k] * rsqrtf((float)(cnt[nl] + 1))
                        : 0.0f;
    }
}

__device__ __forceinline__ void add_h8(float* a, int4 raw) {
    const __half2* p = (const __half2*)&raw;
#pragma unroll
    for (int i = 0; i < 4; ++i) {
        float2 f = __half22float2(p[i]);
        a[2 * i] += f.x;
        a[2 * i + 1] += f.y;
    }
}

// ---- FUSED layers 1+2 (R24): lane-per-edge x~ row gather + W1 + MFMA ----
// Lane q owns edge j+q: 1 coalesced csr load + 2 float4 gathers per 16
// edges, NO shfls in the loop. float8 acc; one 16-lane xor tree per node.

__global__ __launch_bounds__(256) void k_aggx_gemm(
        const int* __restrict__ rowptr, const int* __restrict__ csr,
        const float* __restrict__ xt, const float* __restrict__ b,
        const float* __restrict__ dinv, const float* __restrict__ W1,
        const __half* __restrict__ Wf, __half* __restrict__ hout,
        int n_nodes) {
    __shared__ __half act[16 * 72];
    __shared__ float W1s[7 * HID];
    const int t = threadIdx.x;
    const int n0 = blockIdx.x * 16;
    const int nl = t >> 4;          // local node 0..15
    const int node = n0 + nl;
    const int l16 = t & 15;
    const float4* xt4 = (const float4*)xt;
    const float4* b4 = (const float4*)b;

    for (int i = t; i < 7 * HID; i += 256) W1s[i] = W1[i];

    float acc8[8];
#pragma unroll
    for (int i = 0; i < 8; ++i) acc8[i] = 0.0f;

    float4 av = make_float4(0.0f, 0.0f, 0.0f, 0.0f);
    float dv = 0.0f;
    if (node < n_nodes) {
        int beg = rowptr[node], end = rowptr[node + 1];
        dv = dinv[node];
        if (l16 == 0) {                    // self term, once
            float4 s0 = xt4[(size_t)node * 2];
            float4 s1 = xt4[(size_t)node * 2 + 1];
            acc8[0] += s0.x; acc8[1] += s0.y; acc8[2] += s0.z; acc8[3] += s0.w;
            acc8[4] += s1.x; acc8[5] += s1.y; acc8[6] += s1.z; acc8[7] += s1.w;
        }
        int j = beg;
        for (; j + 15 < end; j += 16) {    // 16 edges: 1 csr + 2 gathers
            int e = csr[j + l16];
            float4 r0 = xt4[(size_t)e * 2];
            float4 r1 = xt4[(size_t)e * 2 + 1];
            acc8[0] += r0.x; acc8[1] += r0.y; acc8[2] += r0.z; acc8[3] += r0.w;
            acc8[4] += r1.x; acc8[5] += r1.y; acc8[6] += r1.z; acc8[7] += r1.w;
        }
        int rem = end - j;
        if (l16 < rem) {
            int e = csr[j + l16];
            float4 r0 = xt4[(size_t)e * 2];
            float4 r1 = xt4[(size_t)e * 2 + 1];
            acc8[0] += r0.x; acc8[1] += r0.y; acc8[2] += r0.z; acc8[3] += r0.w;
            acc8[4] += r1.x; acc8[5] += r1.y; acc8[6] += r1.z; acc8[7] += r1.w;
        }
    }
    // 16-lane xor tree: every lane ends with the full 7-comp aggregate
#pragma unroll
    for (int o = 8; o; o >>= 1)
#pragma unroll
        for (int i = 0; i < 7; ++i)
            acc8[i] += __shfl_xor(acc8[i], o, 16);

    if (node < n_nodes) {
        float4 bb = b4[l16];
#pragma unroll
        for (int i = 0; i < 4; ++i) {
            int c = l16 * 4 + i;
            float dot = 0.0f;
#pragma unroll
            for (int k = 0; k < 7; ++k) dot += acc8[k] * W1s[k * HID + c];
            float v = ((const float*)&bb)[i] + dv * dot;
            ((float*)&av)[i] = fmaxf(v, 0.0f);     // relu -> gemm input
        }
    }
    {   // stage act tile: row nl, cols l16*4..+3 (8B store)
        __half2 p0 = __floats2half2_rn(av.x, av.y);
        __half2 p1 = __floats2half2_rn(av.z, av.w);
        int2 pk;
        pk.x = *(int*)&p0;
        pk.y = *(int*)&p1;
        *(int2*)&act[nl * 72 + l16 * 4] = pk;
    }
    __syncthreads();

    const int wave = t >> 6, lane = t & 63;
    const int quad = lane >> 4, m = lane & 15;
    const half8* Wf8 = (const half8*)Wf;
    f32x4 acc = {0.0f, 0.0f, 0.0f, 0.0f};
#pragma unroll
    for (int kt = 0; kt < 2; ++kt) {
        half8 a = *(const half8*)&act[m * 72 + kt * 32 + quad * 8];
        half8 bv = Wf8[(kt * 4 + wave) * 64 + lane];
        acc = __builtin_amdgcn_mfma_f32_16x16x32_f16(a, bv, acc, 0, 0, 0);
    }
#pragma unroll
    for (int r = 0; r < 4; ++r) {
        int nd = n0 + quad * 4 + r;
        if (nd < n_nodes)
            hout[(size_t)nd * HID + wave * 16 + m] =
                __float2half(acc[r] * dinv[nd]);
    }
}

// ---- pass 2 (R24): agg h2 via dwordx4 slices + relu2 + z epilogue -------
// Lane = (c_blk 0..7) x (half 0..1): each gather instr reads 2 FULL 128B
// rows contiguously (lanes 0-7 = row A slices, 8-15 = row B). 4 gather
// instrs per 8 edges (was 8). float8 acc; epilogue: half-combine xor(8),
// bias+relu, W3l dot, xor tree over c_blk, 8B write.

__global__ __launch_bounds__(256) void k_agg_z(
        const int* __restrict__ rowptr, const int* __restrict__ csr,
        const __half* __restrict__ h, const float* __restrict__ b,
        const float* __restrict__ dinv, const float* __restrict__ W3l,
        float2* __restrict__ zbuf, int n_nodes) {
    const int t = threadIdx.x;
    const int n0 = blockIdx.x * 16;
    const int nl = t >> 4;          // local node 0..15
    const int node = n0 + nl;
    const int l16 = t & 15;
    const int cb = l16 & 7;         // my 8-channel block (16B slice)
    const int hf = l16 >> 3;        // even/odd edge half
    const int4* h16 = (const int4*)h;   // 16B units; row = 8 units

    float w3l0[8], w3l1[8], bb8[8];
#pragma unroll
    for (int i = 0; i < 8; ++i) {
        w3l0[i] = W3l[(cb * 8 + i) * 2 + 0];
        w3l1[i] = W3l[(cb * 8 + i) * 2 + 1];
        bb8[i] = b[cb * 8 + i];
    }

    float acc8[8];
#pragma unroll
    for (int i = 0; i < 8; ++i) acc8[i] = 0.0f;

    float dv = 0.0f;
    if (node < n_nodes) {
        int beg = rowptr[node], end = rowptr[node + 1];
        dv = dinv[node];
        if (hf == 0)                       // self h' slice, once
            add_h8(acc8, h16[(size_t)node * 8 + cb]);
        int j = beg;
        for (; j + 7 < end; j += 8) {      // 8 edges: 1 csr + 4 gathers
            int e8 = csr[j + (l16 & 7)];
            int4 r[4];
#pragma unroll
            for (int q = 0; q < 4; ++q) {
                int sid = __shfl(e8, 2 * q + hf, 8);
                r[q] = h16[(size_t)sid * 8 + cb];
            }
#pragma unroll
            for (int q = 0; q < 4; ++q) add_h8(acc8, r[q]);
        }
        if (j + 3 < end) {                 // 4 edges: 2 gathers
            int e4 = csr[j + (l16 & 3)];
            int4 r[2];
#pragma unroll
            for (int q = 0; q < 2; ++q) {
                int sid = __shfl(e4, 2 * q + hf, 4);
                r[q] = h16[(size_t)sid * 8 + cb];
            }
            add_h8(acc8, r[0]);
            add_h8(acc8, r[1]);
            j += 4;
        }
        for (; j < end; ++j)               // <=3 edges: half 0 only
            if (hf == 0) add_h8(acc8, h16[(size_t)csr[j] * 8 + cb]);
    }
    // combine even/odd halves (lanes l16 and l16^8 hold same cb)
#pragma unroll
    for (int i = 0; i < 8; ++i) acc8[i] += __shfl_xor(acc8[i], 8, 16);
    // relu2 + dot with W3l columns
    float p0 = 0.0f, p1 = 0.0f;
#pragma unroll
    for (int i = 0; i < 8; ++i) {
        float v = fmaxf(bb8[i] + dv * acc8[i], 0.0f);
        p0 += v * w3l0[i];
        p1 += v * w3l1[i];
    }
#pragma unroll
    for (int o = 4; o; o >>= 1) {
        p0 += __shfl_xor(p0, o, 16);
        p1 += __shfl_xor(p1, o, 16);
    }
    if (node < n_nodes && l16 == 0)
        zbuf[node] = make_float2(p0 * dv, p1 * dv);
}

// ---- pass 3 (R23): aggregate z (8B rows, L2-resident) -> graph partials -

__global__ __launch_bounds__(256) void k_zagg_part(
        const int* __restrict__ rowptr, const int* __restrict__ csr,
        const float2* __restrict__ zbuf, const float* __restrict__ dinv,
        const int* __restrict__ batch, float* __restrict__ partv,
        int* __restrict__ partg, float* __restrict__ gsum, int n_nodes) {
    __shared__ float2 ys[16];
    __shared__ int bg[16];
    const int t = threadIdx.x;
    const int n0 = blockIdx.x * 16;
    const int nl = t >> 4;
    const int node = n0 + nl;
    const int q = t & 15;

    if (t < 16) {
        int nd = n0 + t;
        bg[t] = (nd < n_nodes) ? batch[nd] : -1;
    }

    float2 yv = make_float2(0.0f, 0.0f);
    if (node < n_nodes) {
        int beg = rowptr[node], end = rowptr[node + 1];
        float2 acc = make_float2(0.0f, 0.0f);
        if (q == 0) acc = zbuf[node];          // self-loop
        int j = beg;
        for (; j + 15 < end; j += 16) {        // 16 edges/iter, 1 gather instr
            int e = csr[j + q];
            float2 v = zbuf[e];
            acc.x += v.x; acc.y += v.y;
        }
        int rem = end - j;
        if (q < rem) {
            int e = csr[j + q];
            float2 v = zbuf[e];
            acc.x += v.x; acc.y += v.y;
        }
#pragma unroll
        for (int o = 8; o; o >>= 1) {
            acc.x += __shfl_xor(acc.x, o, 16);
            acc.y += __shfl_xor(acc.y, o, 16);
        }
        float dv = dinv[node];
        yv = make_float2(acc.x * dv, acc.y * dv);
    }
    if (q == 0) ys[nl] = yv;
    __syncthreads();

    if (t == 0) {           // run-length reduce 16 nodes -> <=2 graph slots
        const int g0 = bg[0];
        const int g15 = bg[15];
        float2 s0 = make_float2(0.0f, 0.0f), s1 = make_float2(0.0f, 0.0f);
        for (int i = 0; i < 16; ++i) {
            int g = bg[i];
            float2 v = ys[i];
            if (g == g0) { s0.x += v.x; s0.y += v.y; }
            else if (g == g15) { s1.x += v.x; s1.y += v.y; }
            else if (g >= 0) {                 // ~never (graph <=14 nodes)
                atomicAdd(&gsum[g * 2 + 0], v.x);
                atomicAdd(&gsum[g * 2 + 1], v.y);
            }
        }
        partv[(size_t)blockIdx.x * 4 + 0] = s0.x;
        partv[(size_t)blockIdx.x * 4 + 1] = s0.y;
        partv[(size_t)blockIdx.x * 4 + 2] = s1.x;
        partv[(size_t)blockIdx.x * 4 + 3] = s1.y;
        partg[blockIdx.x * 2 + 0] = g0;
        partg[blockIdx.x * 2 + 1] = (g15 != g0) ? g15 : -1;
    }
}

// ---- pool over float2 partials + head bias: one block per graph ---------

__global__ __launch_bounds__(256) void k_pool_head(
        const float* __restrict__ partv, const int* __restrict__ partg,
        const float* __restrict__ gsum, const int* __restrict__ batch,
        const float* __restrict__ b3, const float* __restrict__ Wl,
        const float* __restrict__ bl, float* __restrict__ out, int n_nodes) {
    int g = blockIdx.x;
    int lo = 0, hi = n_nodes;
    while (lo < hi) { int m = (lo + hi) >> 1; if (batch[m] < g) lo = m + 1; else hi = m; }
    int nstart = lo;
    hi = n_nodes;
    while (lo < hi) { int m = (lo + hi) >> 1; if (batch[m] < g + 1) lo = m + 1; else hi = m; }
    int nend = lo;

    const int t = threadIdx.x;
    float ax = 0.0f, ay = 0.0f;
    if (nend > nstart) {
        int b0 = nstart >> 4, b1 = (nend - 1) >> 4;
        for (int b = b0 + t; b <= b1; b += 256) {
            if (partg[b * 2 + 0] == g) { ax += partv[(size_t)b * 4 + 0]; ay += partv[(size_t)b * 4 + 1]; }
            if (partg[b * 2 + 1] == g) { ax += partv[(size_t)b * 4 + 2]; ay += partv[(size_t)b * 4 + 3]; }
        }
    }
    __shared__ float rx[256], ry[256];
    rx[t] = ax; ry[t] = ay;
    __syncthreads();
    for (int s2 = 128; s2; s2 >>= 1) {
        if (t < s2) { rx[t] += rx[t + s2]; ry[t] += ry[t + s2]; }
        __syncthreads();
    }
    if (t < 2) {
        float cntf = fmaxf((float)(nend - nstart), 1.0f);
        float s = ((t == 0) ? rx[0] : ry[0]) + gsum[g * 2 + t];
        float hb = 0.0f;                     // b3 @ Wl (column t)
        for (int c = 0; c < HID; ++c) hb += b3[c] * Wl[c * 2 + t];
        out[g * 2 + t] = s / cntf + hb + bl[t];
    }
}

// -------------------------------------------------------------------------

extern "C" void kernel_launch(void* const* d_in, const int* in_sizes, int n_in,
                              void* d_out, int out_size, void* d_ws, size_t ws_size,
                              hipStream_t stream) {
    const float* x     = (const float*)d_in[0];
    const int*   ei    = (const int*)d_in[1];
    const int*   batch = (const int*)d_in[2];
    const float* W1    = (const float*)d_in[3];
    const float* b1    = (const float*)d_in[4];
    const float* W2    = (const float*)d_in[5];
    const float* b2    = (const float*)d_in[6];
    const float* W3    = (const float*)d_in[7];
    const float* b3    = (const float*)d_in[8];
    const float* Wl    = (const float*)d_in[9];
    const float* bl    = (const float*)d_in[10];
    float* out = (float*)d_out;

    const int N = in_sizes[0] / 7;     // 100000
    const int E = in_sizes[1] / 2;     // 1250000
    const int* src = ei;
    const int* dst = ei + E;

    const int nbkt   = (N + BKTSZ - 1) >> BKTSH;          // 196
    const int nchunk = (E + CHUNK - 1) / CHUNK;           // 306
    const int lenH   = nbkt * nchunk;
    const int nscan  = (lenH + 1023) / 1024;              // 59 (<=64)

    char* ws = (char*)d_ws;
    size_t off = 0;
    auto carve = [&](size_t bytes) {
        void* p = ws + off;
        off = (off + bytes + 255) & ~(size_t)255;
        return p;
    };
    int*    H      = (int*)carve((size_t)lenH * 4);
    int*    Hs     = (int*)carve((size_t)lenH * 4);
    int*    bsum   = (int*)carve(512 * 4);
    int*    packed = (int*)carve((size_t)E * 4);
    int*    csr    = (int*)carve((size_t)E * 4);
    int*    rowptr = (int*)carve((size_t)(N + 1) * 4);
    float*  dinv   = (float*)carve((size_t)N * 4);
    __half* Wf2    = (__half*)carve(4096 * 2);
    float*  W3l    = (float*)carve(128 * 4);
    float*  gsum   = (float*)carve((size_t)NGRAPHS * 2 * 4);
    float*  xt     = (float*)carve((size_t)(N + 64) * 8 * 4);     // padded x~
    __half* bufB   = (__half*)carve((size_t)(N + 64) * HID * 2);  // +pad rows
    float2* zbuf   = (float2*)carve((size_t)(N + 64) * 8);

    const int nb_agg = (N + 15) / 16;      // 6250
    float* partv = (float*)carve((size_t)nb_agg * 4 * 4);
    int*   partg = (int*)carve((size_t)nb_agg * 2 * 4);

    // ---- CSR build (LDS counting sort, 3-pass scan pipeline)
    k_hist<<<nchunk, 256, 0, stream>>>(dst, W2, W3, Wl, Wf2, W3l, H, gsum,
                                       E, nbkt, nchunk);
    k_scan<<<nscan, 256, 0, stream>>>(H, Hs, bsum, lenH);
    k_scatter<<<nchunk, 256, 0, stream>>>(src, dst, Hs, bsum, packed,
                                          E, nbkt, nchunk, nscan);
    // csr_build also emits x~ = x*dinv (padded 8-float rows)
    k_csr_build<<<nbkt, 256, 0, stream>>>(packed, Hs, bsum, rowptr, dinv, csr,
                                          x, xt, E, N, nbkt, nchunk, nscan);

    // ---- fused layers 1+2 (x~ agg + W1 matvec + W2 MFMA) -> bufB
    k_aggx_gemm<<<nb_agg, 256, 0, stream>>>(rowptr, csr, xt, b1, dinv, W1,
                                            Wf2, bufB, N);
    // ---- pass 2: agg bufB + relu2 + z = dinv*(relu2@W3l) (8B/node)
    k_agg_z<<<nb_agg, 256, 0, stream>>>(rowptr, csr, bufB, b2, dinv, W3l,
                                        zbuf, N);
    // ---- pass 3: agg z (8B rows) -> per-block graph partials
    k_zagg_part<<<nb_agg, 256, 0, stream>>>(rowptr, csr, zbuf, dinv, batch,
                                            partv, partg, gsum, N);

    // ---- pool over partials + head (one block per graph)
    k_pool_head<<<NGRAPHS, 256, 0, stream>>>(partv, partg, gsum, batch,
                                             b3, Wl, bl, out, N);
}